// Round 8
// baseline (313.328 us; speedup 1.0000x reference)
//
#include <hip/hip_runtime.h>
#include <cstdint>
#include <climits>
#include <cstddef>

typedef unsigned long long u64;

#define B_ROWS 65536
#define BN_EPS 1e-5

// ---------------------------------------------------------------------------
// Layouts:
//   bitsx (x/layer0 input): 13 words/row, float4-INTERLEAVED order (verified
//     rounds 3-7): word k=4*cg+e (cg<3): bit l <-> col cg*256+4l+e; word 12 =
//     cols 768..783 as 4 nibbles. Stored col-major bitsx[k*65536+row].
//   w0 -> wb0p e-plane: wb0p[((c&7)*13+k)*32+(c>>3)] = word k of out-col c.
//   layers 1..4 activations: NATURAL order, word W bit b <-> col 64W+b.
//     Global bits col-major bitsL[W*65536+row]; in-kernel row-major bytes
//     sBin[row*32+byte] (byte ct = cols 8ct..8ct+7).
//   w1..w3 -> wbNp natural e-plane: wbNp[L][((c&7)*4+W)*32+(c>>3)].
//   w4 -> w4b[c*4+W] natural words (broadcast).
//   v exists only for layer 4 (v4, int16 [row][10]).
// Relay scheme: kernel L re-runs layer-L GEMM (thresholds known from stats),
// binarizes into LDS + 2MB global bits, then runs layer-(L+1) stats GEMM
// from LDS in the same launch. Exact integer math end-to-end (absmax=0).
// ---------------------------------------------------------------------------

// ---------------------------------------------------------------------------
// prep_w: pack all weights + zero stat accumulators. Grid 258.
// ---------------------------------------------------------------------------
__global__ __launch_bounds__(256) void prep_w(
    const float* __restrict__ w0, const float* __restrict__ w1,
    const float* __restrict__ w2, const float* __restrict__ w3,
    const float* __restrict__ w4,
    u64* __restrict__ wb0p, u64* __restrict__ wbNp, u64* __restrict__ w4b,
    long long* gsum, long long* gsq, int* gmin, int* gmax, double* colsum)
{
    const int lane = threadIdx.x & 63;
    const int wv   = threadIdx.x >> 6;
    const int b    = blockIdx.x;

    if (b < 64) {
        // ---- w0 -> interleaved e-plane ----
        const int c  = b * 4 + wv;
        const int pb = (c & 7) * 13;
        const int g  = c >> 3;
        const float4* row = (const float4*)(w0 + (size_t)c * 784);
#pragma unroll
        for (int cg = 0; cg < 3; ++cg) {
            const float4 f = row[cg*64 + lane];
            const u64 e0 = __ballot(f.x >= 0.0f);
            const u64 e1 = __ballot(f.y >= 0.0f);
            const u64 e2 = __ballot(f.z >= 0.0f);
            const u64 e3 = __ballot(f.w >= 0.0f);
            if (lane == 0) {
                wb0p[(pb + cg*4+0)*32 + g] = e0;
                wb0p[(pb + cg*4+1)*32 + g] = e1;
                wb0p[(pb + cg*4+2)*32 + g] = e2;
                wb0p[(pb + cg*4+3)*32 + g] = e3;
            }
        }
        float4 f = make_float4(-1.f, -1.f, -1.f, -1.f);
        if (lane < 4) f = row[192 + lane];
        const u64 e0 = __ballot(f.x >= 0.0f) & 0xF;
        const u64 e1 = __ballot(f.y >= 0.0f) & 0xF;
        const u64 e2 = __ballot(f.z >= 0.0f) & 0xF;
        const u64 e3 = __ballot(f.w >= 0.0f) & 0xF;
        if (lane == 0) wb0p[(pb + 12)*32 + g] = e0 | (e1 << 4) | (e2 << 8) | (e3 << 12);
    } else if (b < 256) {
        // ---- w1..w3 -> natural e-plane ----
        const int idx = (b - 64) * 4 + wv;           // 0..767
        const int L = idx >> 8, c = idx & 255;
        const float* ws = (L == 0) ? w1 : (L == 1) ? w2 : w3;
        const int pb = (c & 7) * 4;
        const int g  = c >> 3;
#pragma unroll
        for (int W = 0; W < 4; ++W) {
            const u64 m = __ballot(ws[(size_t)c * 256 + W*64 + lane] >= 0.0f);
            if (lane == 0) wbNp[L*1024 + (pb + W)*32 + g] = m;
        }
    } else if (b == 256) {
        for (int c = wv; c < 10; c += 4)
#pragma unroll
            for (int W = 0; W < 4; ++W) {
                const u64 m = __ballot(w4[(size_t)c * 256 + W*64 + lane] >= 0.0f);
                if (lane == 0) w4b[c*4 + W] = m;
            }
    } else {
        for (int i = threadIdx.x; i < 1040; i += 256) { gsum[i] = 0; gsq[i] = 0; }
        if (threadIdx.x < 16) {
            gmin[threadIdx.x] = INT_MAX;
            gmax[threadIdx.x] = INT_MIN;
            colsum[threadIdx.x] = 0.0;
        }
    }
}

// ---------------------------------------------------------------------------
// bn_threshold: exact integer binarization threshold from exact stats.
// ---------------------------------------------------------------------------
__device__ __forceinline__ void bn_threshold(long long sv, long long qv,
    float gaf, float bef, int& sg, int& t)
{
    const double mean = (double)sv / (double)B_ROWS;
    double var = (double)qv / (double)B_ROWS - mean * mean;
    if (var < 0.0) var = 0.0;
    const double rs    = 1.0 / sqrt(var + BN_EPS);
    const double scale = (double)gaf * rs;
    const double bt    = (double)bef;
    if (scale > 0.0) {
        const double tt = fmin(fmax(mean - bt / scale, -1e6), 1e6);
        sg = 1; t = (int)ceil(tt);
    } else if (scale < 0.0) {
        const double tt = fmin(fmax(mean - bt / scale, -1e6), 1e6);
        sg = -1; t = (int)(-floor(tt));
    } else { sg = 0; t = (bt >= 0.0) ? INT_MIN : 1; }
}

// ---------------------------------------------------------------------------
// gemm_stats: 128 rows x 256 cols popcount GEMM -> exact per-col sum/sumsq.
// ct=tid&31 -> cols 8ct..8ct+7; rt=tid>>5 -> rows rt+16j. A indexed
// sA[k*SK + row*SR] (col-major: SK=128,SR=1; row-major u64: SK=1,SR=4).
// A reads broadcast (2 addrs/wave); W reads stride-8B (2-way, free).
// Counts packed 2/u32. shfl fold -> LDS atomics -> 256 global atomics.
// ---------------------------------------------------------------------------
template<int KW, int SK, int SR>
__device__ __forceinline__ void gemm_stats(const u64* __restrict__ sA,
    const u64* __restrict__ sWp, int K,
    long long* gsumL, long long* gsqL, int* sS, int* sQ)
{
    const int tid = threadIdx.x;
    const int ct  = tid & 31;
    const int rt  = tid >> 5;

    unsigned p2[8][4];
#pragma unroll
    for (int j = 0; j < 8; ++j)
#pragma unroll
        for (int e2 = 0; e2 < 4; ++e2) p2[j][e2] = 0;

#pragma unroll 1
    for (int k = 0; k < KW; ++k) {
        u64 a[8];
#pragma unroll
        for (int j = 0; j < 8; ++j) a[j] = sA[k*SK + (rt + 16*j)*SR];
        u64 w[8];
#pragma unroll
        for (int e = 0; e < 8; ++e) w[e] = sWp[(e*KW + k)*32 + ct];
#pragma unroll
        for (int j = 0; j < 8; ++j)
#pragma unroll
            for (int e2 = 0; e2 < 4; ++e2)
                p2[j][e2] += (unsigned)__popcll(a[j] ^ w[2*e2])
                           + ((unsigned)__popcll(a[j] ^ w[2*e2+1]) << 16);
    }

    int s8[8], q8[8];
#pragma unroll
    for (int e = 0; e < 8; ++e) { s8[e] = 0; q8[e] = 0; }
#pragma unroll
    for (int j = 0; j < 8; ++j)
#pragma unroll
        for (int e2 = 0; e2 < 4; ++e2) {
            const int v0 = K - 2 * (int)(p2[j][e2] & 0xFFFFu);
            const int v1 = K - 2 * (int)(p2[j][e2] >> 16);
            s8[2*e2]   += v0; q8[2*e2]   += v0*v0;
            s8[2*e2+1] += v1; q8[2*e2+1] += v1*v1;
        }
#pragma unroll
    for (int e = 0; e < 8; ++e) {
        s8[e] += __shfl_xor(s8[e], 32);
        q8[e] += __shfl_xor(q8[e], 32);
    }
    if ((tid & 63) < 32) {
#pragma unroll
        for (int e = 0; e < 8; ++e) {
            atomicAdd(&sS[8*ct + e], s8[e]);
            atomicAdd(&sQ[8*ct + e], q8[e]);
        }
    }
    __syncthreads();
    if (tid < 256) {
        atomicAdd((u64*)&gsumL[tid], (u64)(long long)sS[tid]);
        atomicAdd((u64*)&gsqL[tid],  (u64)(long long)sQ[tid]);
    }
}

// ---------------------------------------------------------------------------
// gemm_bin: recompute GEMM + integer threshold -> natural-order bytes in LDS.
// Thread (ct,rt) owns cols 8ct..8ct+7 of rows rt+16j -> byte ct of each row.
// ---------------------------------------------------------------------------
template<int KW, int SK, int SR>
__device__ __forceinline__ void gemm_bin(const u64* __restrict__ sA,
    const u64* __restrict__ sWp, int K,
    const int* __restrict__ sSgn, const int* __restrict__ sThr,
    unsigned char* __restrict__ sBinB)
{
    const int tid = threadIdx.x;
    const int ct  = tid & 31;
    const int rt  = tid >> 5;
    const int c0  = ct << 3;

    unsigned p2[8][4];
#pragma unroll
    for (int j = 0; j < 8; ++j)
#pragma unroll
        for (int e2 = 0; e2 < 4; ++e2) p2[j][e2] = 0;

#pragma unroll 1
    for (int k = 0; k < KW; ++k) {
        u64 a[8];
#pragma unroll
        for (int j = 0; j < 8; ++j) a[j] = sA[k*SK + (rt + 16*j)*SR];
        u64 w[8];
#pragma unroll
        for (int e = 0; e < 8; ++e) w[e] = sWp[(e*KW + k)*32 + ct];
#pragma unroll
        for (int j = 0; j < 8; ++j)
#pragma unroll
            for (int e2 = 0; e2 < 4; ++e2)
                p2[j][e2] += (unsigned)__popcll(a[j] ^ w[2*e2])
                           + ((unsigned)__popcll(a[j] ^ w[2*e2+1]) << 16);
    }

    int sg[8], th[8];
    *(int4*)&sg[0] = *(const int4*)&sSgn[c0];
    *(int4*)&sg[4] = *(const int4*)&sSgn[c0 + 4];
    *(int4*)&th[0] = *(const int4*)&sThr[c0];
    *(int4*)&th[4] = *(const int4*)&sThr[c0 + 4];

#pragma unroll
    for (int j = 0; j < 8; ++j) {
        unsigned byteV = 0;
#pragma unroll
        for (int e2 = 0; e2 < 4; ++e2) {
            const int v0 = K - 2 * (int)(p2[j][e2] & 0xFFFFu);
            const int v1 = K - 2 * (int)(p2[j][e2] >> 16);
            byteV |= (unsigned)(sg[2*e2]  *v0 >= th[2*e2])   << (2*e2);
            byteV |= (unsigned)(sg[2*e2+1]*v1 >= th[2*e2+1]) << (2*e2+1);
        }
        sBinB[(rt + 16*j)*32 + ct] = (unsigned char)byteV;
    }
}

// ---------------------------------------------------------------------------
// prep_x_gemm: pack 128 x-rows (interleaved) into LDS + bitsx global, then
// layer-0 stats GEMM from LDS. GEMM VALU hides under the 205MB HBM x read.
// ---------------------------------------------------------------------------
__global__ __launch_bounds__(512, 2) void prep_x_gemm(
    const float* __restrict__ x, const u64* __restrict__ wb0p,
    u64* __restrict__ bitsx, long long* gsum, long long* gsq)
{
    __shared__ __align__(16) u64 sA[13*128];
    __shared__ __align__(16) u64 sWp[13*8*32];
    __shared__ int sS[256], sQ[256];
    const int tid  = threadIdx.x;
    const int lane = tid & 63;
    const int wv   = tid >> 6;
    const int row0 = blockIdx.x * 128;

    for (int i = tid; i < 13*8*32; i += 512) sWp[i] = wb0p[i];
    if (tid < 256) { sS[tid] = 0; sQ[tid] = 0; }

    for (int i = 0; i < 16; ++i) {
        const int r   = wv * 16 + i;
        const int row = row0 + r;
        const float4* xr = (const float4*)(x + (size_t)row * 784);
#pragma unroll
        for (int cg = 0; cg < 3; ++cg) {
            const float4 f = xr[cg*64 + lane];
            const u64 e0 = __ballot(f.x >= 0.5f);
            const u64 e1 = __ballot(f.y >= 0.5f);
            const u64 e2 = __ballot(f.z >= 0.5f);
            const u64 e3 = __ballot(f.w >= 0.5f);
            if (lane == 0) {
                sA[(cg*4+0)*128 + r] = e0; bitsx[(size_t)(cg*4+0)*65536 + row] = e0;
                sA[(cg*4+1)*128 + r] = e1; bitsx[(size_t)(cg*4+1)*65536 + row] = e1;
                sA[(cg*4+2)*128 + r] = e2; bitsx[(size_t)(cg*4+2)*65536 + row] = e2;
                sA[(cg*4+3)*128 + r] = e3; bitsx[(size_t)(cg*4+3)*65536 + row] = e3;
            }
        }
        float4 f = make_float4(-1.f, -1.f, -1.f, -1.f);
        if (lane < 4) f = xr[192 + lane];
        const u64 e0 = __ballot(f.x >= 0.5f) & 0xF;
        const u64 e1 = __ballot(f.y >= 0.5f) & 0xF;
        const u64 e2 = __ballot(f.z >= 0.5f) & 0xF;
        const u64 e3 = __ballot(f.w >= 0.5f) & 0xF;
        if (lane == 0) {
            const u64 wtail = e0 | (e1 << 4) | (e2 << 8) | (e3 << 12);
            sA[12*128 + r] = wtail;
            bitsx[(size_t)12*65536 + row] = wtail;
        }
    }
    __syncthreads();
    gemm_stats<13, 128, 1>(sA, sWp, 784, gsum, gsq, sS, sQ);
}

// ---------------------------------------------------------------------------
// relay13: recompute L0 (bitsx x wb0p, thr0) -> bits0 (natural) + L1 stats
// GEMM from LDS.
// ---------------------------------------------------------------------------
__global__ __launch_bounds__(512, 2) void relay13(
    const u64* __restrict__ bitsx, const u64* __restrict__ wb0p,
    const long long* __restrict__ gsumP, const long long* __restrict__ gsqP,
    const float* __restrict__ gaP, const float* __restrict__ beP,
    const u64* __restrict__ wbNpN, u64* __restrict__ bitsOut,
    long long* gsumC, long long* gsqC)
{
    __shared__ __align__(16) u64 sA[13*128];
    __shared__ __align__(16) u64 sWpI[13*8*32];
    __shared__ __align__(16) u64 sWpN[4*8*32];
    __shared__ __align__(16) u64 sBin[128*4];
    __shared__ int sSgn[256], sThr[256], sS[256], sQ[256];
    const int tid  = threadIdx.x;
    const int row0 = blockIdx.x * 128;

    for (int i = tid; i < 13*128; i += 512)
        sA[i] = bitsx[(size_t)(i >> 7)*65536 + row0 + (i & 127)];
    for (int i = tid; i < 13*8*32; i += 512) sWpI[i] = wb0p[i];
    for (int i = tid; i < 4*8*32;  i += 512) sWpN[i] = wbNpN[i];
    if (tid < 256) {
        int sg, t;
        bn_threshold(gsumP[tid], gsqP[tid], gaP[tid], beP[tid], sg, t);
        sSgn[tid] = sg; sThr[tid] = t;
        sS[tid] = 0; sQ[tid] = 0;
    }
    __syncthreads();

    gemm_bin<13, 128, 1>(sA, sWpI, 784, sSgn, sThr, (unsigned char*)sBin);
    __syncthreads();

    { const int W = tid >> 7, r = tid & 127;
      bitsOut[(size_t)W*65536 + row0 + r] = sBin[r*4 + W]; }
    gemm_stats<4, 1, 4>(sBin, sWpN, 256, gsumC, gsqC, sS, sQ);
}

// ---------------------------------------------------------------------------
// relay4: recompute mid layer (bitsIn x wIn, thr) -> bitsOut + next stats.
// ---------------------------------------------------------------------------
__global__ __launch_bounds__(512, 2) void relay4(
    const u64* __restrict__ bitsIn, const u64* __restrict__ wbNpI,
    const long long* __restrict__ gsumP, const long long* __restrict__ gsqP,
    const float* __restrict__ gaP, const float* __restrict__ beP,
    const u64* __restrict__ wbNpN, u64* __restrict__ bitsOut,
    long long* gsumC, long long* gsqC)
{
    __shared__ __align__(16) u64 sBinI[128*4];
    __shared__ __align__(16) u64 sWpI[4*8*32];
    __shared__ __align__(16) u64 sWpN[4*8*32];
    __shared__ __align__(16) u64 sBinO[128*4];
    __shared__ int sSgn[256], sThr[256], sS[256], sQ[256];
    const int tid  = threadIdx.x;
    const int row0 = blockIdx.x * 128;

    { const int W = tid >> 7, r = tid & 127;
      sBinI[r*4 + W] = bitsIn[(size_t)W*65536 + row0 + r]; }
    for (int i = tid; i < 4*8*32; i += 512) { sWpI[i] = wbNpI[i]; sWpN[i] = wbNpN[i]; }
    if (tid < 256) {
        int sg, t;
        bn_threshold(gsumP[tid], gsqP[tid], gaP[tid], beP[tid], sg, t);
        sSgn[tid] = sg; sThr[tid] = t;
        sS[tid] = 0; sQ[tid] = 0;
    }
    __syncthreads();

    gemm_bin<4, 1, 4>(sBinI, sWpI, 256, sSgn, sThr, (unsigned char*)sBinO);
    __syncthreads();

    { const int W = tid >> 7, r = tid & 127;
      bitsOut[(size_t)W*65536 + row0 + r] = sBinO[r*4 + W]; }
    gemm_stats<4, 1, 4>(sBinO, sWpN, 256, gsumC, gsqC, sS, sQ);
}

// ---------------------------------------------------------------------------
// final4: recompute L3 (bits2 x w3, thr3) -> bits in LDS, then L4 (10 cols)
// per-row directly from LDS -> v4 + exact sum/sq/min/max stats.
// ---------------------------------------------------------------------------
__global__ __launch_bounds__(512, 2) void final4(
    const u64* __restrict__ bitsIn, const u64* __restrict__ wbNpI,
    const long long* __restrict__ gsumP, const long long* __restrict__ gsqP,
    const float* __restrict__ gaP, const float* __restrict__ beP,
    const u64* __restrict__ w4b, short* __restrict__ v4,
    long long* gsum4, long long* gsq4, int* gmin, int* gmax)
{
    __shared__ __align__(16) u64 sBinI[128*4];
    __shared__ __align__(16) u64 sWpI[4*8*32];
    __shared__ __align__(16) u64 sBinO[128*4];
    __shared__ u64 sW4[40];
    __shared__ int sSgn[256], sThr[256];
    __shared__ int sS4[10], sQ4[10], sMn[10], sMx[10];
    const int tid  = threadIdx.x;
    const int row0 = blockIdx.x * 128;

    { const int W = tid >> 7, r = tid & 127;
      sBinI[r*4 + W] = bitsIn[(size_t)W*65536 + row0 + r]; }
    for (int i = tid; i < 4*8*32; i += 512) sWpI[i] = wbNpI[i];
    if (tid < 40) sW4[tid] = w4b[tid];
    if (tid < 256) {
        int sg, t;
        bn_threshold(gsumP[tid], gsqP[tid], gaP[tid], beP[tid], sg, t);
        sSgn[tid] = sg; sThr[tid] = t;
    }
    if (tid < 10) { sS4[tid] = 0; sQ4[tid] = 0; sMn[tid] = INT_MAX; sMx[tid] = INT_MIN; }
    __syncthreads();

    gemm_bin<4, 1, 4>(sBinI, sWpI, 256, sSgn, sThr, (unsigned char*)sBinO);
    __syncthreads();

    if (tid < 128) {
        const int r = tid;
        const u64 a0 = sBinO[r*4+0], a1 = sBinO[r*4+1];
        const u64 a2 = sBinO[r*4+2], a3 = sBinO[r*4+3];
#pragma unroll
        for (int c = 0; c < 10; ++c) {
            const int p = (int)__popcll(a0 ^ sW4[c*4+0]) + (int)__popcll(a1 ^ sW4[c*4+1])
                        + (int)__popcll(a2 ^ sW4[c*4+2]) + (int)__popcll(a3 ^ sW4[c*4+3]);
            const int vr = 256 - 2*p;
            v4[(size_t)(row0 + r)*10 + c] = (short)vr;
            atomicAdd(&sS4[c], vr);
            atomicAdd(&sQ4[c], vr*vr);
            atomicMin(&sMn[c], vr);
            atomicMax(&sMx[c], vr);
        }
    }
    __syncthreads();
    if (tid < 10) {
        atomicAdd((u64*)&gsum4[tid], (u64)(long long)sS4[tid]);
        atomicAdd((u64*)&gsq4[tid],  (u64)(long long)sQ4[tid]);
        atomicMin(&gmin[tid], sMn[tid]);
        atomicMax(&gmax[tid], sMx[tid]);
    }
}

// ---------------------------------------------------------------------------
// colsum_kernel: zs/zb (exact from integer min/max) + partial exp-sums.
// ---------------------------------------------------------------------------
__global__ __launch_bounds__(256) void colsum_kernel(
    const short* __restrict__ v4,
    const long long* __restrict__ gsum4, const long long* __restrict__ gsq4,
    const int* __restrict__ gmin, const int* __restrict__ gmax,
    const float* __restrict__ g4, const float* __restrict__ b4,
    double* zsg, double* zbg, double* colsum)
{
    __shared__ double sred[256];
    __shared__ double sZ[2];
    const int c     = blockIdx.x % 10;
    const int chunk = blockIdx.x / 10;
    const int tid   = threadIdx.x;
    if (tid == 0) {
        const double mean = (double)gsum4[c] / (double)B_ROWS;
        double var = (double)gsq4[c] / (double)B_ROWS - mean * mean;
        if (var < 0.0) var = 0.0;
        const double rs    = 1.0 / sqrt(var + BN_EPS);
        const double scale = (double)g4[c] * rs;
        const double bias  = (double)b4[c] - mean * scale;
        const double z1 = scale * (double)gmin[c] + bias;
        const double z2 = scale * (double)gmax[c] + bias;
        const double zb = bias - fmax(z1, z2);
        sZ[0] = scale; sZ[1] = zb;
        zsg[c] = scale; zbg[c] = zb;       // redundant identical writes, benign
    }
    __syncthreads();
    const double zs = sZ[0], zb = sZ[1];
    double acc = 0.0;
    const int r0 = chunk * 1024;
#pragma unroll
    for (int j = 0; j < 4; ++j) {
        const int r = r0 + j*256 + tid;
        acc += exp(zs * (double)v4[(size_t)r*10 + c] + zb);
    }
    sred[tid] = acc; __syncthreads();
    for (int s = 128; s > 0; s >>= 1) {
        if (tid < s) sred[tid] += sred[tid + s];
        __syncthreads();
    }
    if (tid == 0) atomicAdd(&colsum[c], sred[0]);
}

// ---------------------------------------------------------------------------
// out_kernel: out = exp(zs*v + zb) / colsum, coalesced.
// ---------------------------------------------------------------------------
__global__ __launch_bounds__(256) void out_kernel(
    const short* __restrict__ v4, const double* __restrict__ zsg,
    const double* __restrict__ zbg, const double* __restrict__ colsum,
    float* __restrict__ out)
{
    const int idx = blockIdx.x * 256 + threadIdx.x;
    if (idx >= B_ROWS * 10) return;
    const int c = idx % 10;
    out[idx] = (float)(exp(zsg[c] * (double)v4[idx] + zbg[c]) / colsum[c]);
}

// ---------------------------------------------------------------------------
extern "C" void kernel_launch(void* const* d_in, const int* in_sizes, int n_in,
                              void* d_out, int out_size, void* d_ws, size_t ws_size,
                              hipStream_t stream)
{
    const float* x  = (const float*)d_in[0];
    const float* w0 = (const float*)d_in[1];
    const float* g0 = (const float*)d_in[2];
    const float* b0 = (const float*)d_in[3];
    const float* w1 = (const float*)d_in[4];
    const float* g1 = (const float*)d_in[5];
    const float* b1 = (const float*)d_in[6];
    const float* w2 = (const float*)d_in[7];
    const float* g2 = (const float*)d_in[8];
    const float* b2 = (const float*)d_in[9];
    const float* w3 = (const float*)d_in[10];
    const float* g3 = (const float*)d_in[11];
    const float* b3 = (const float*)d_in[12];
    const float* w4 = (const float*)d_in[13];
    const float* g4 = (const float*)d_in[14];
    const float* b4 = (const float*)d_in[15];

    char* p = (char*)d_ws;
    auto alloc = [&](size_t bytes) -> char* {
        char* r = p;
        p += (bytes + 255) & ~(size_t)255;
        return r;
    };
    u64*       bitsx  = (u64*)alloc(13ull*65536*8);
    u64*       bits0  = (u64*)alloc(4ull*65536*8);
    u64*       bits1  = (u64*)alloc(4ull*65536*8);
    u64*       bits2  = (u64*)alloc(4ull*65536*8);
    u64*       wb0p   = (u64*)alloc(13*8*32*8);
    u64*       wbNp   = (u64*)alloc(3*1024*8);
    u64*       w4b    = (u64*)alloc(40*8);
    short*     v4     = (short*)alloc(65536ull*10*2);
    long long* gsum   = (long long*)alloc(1040*8);
    long long* gsq    = (long long*)alloc(1040*8);
    int*       gmin   = (int*)alloc(16*4);
    int*       gmax   = (int*)alloc(16*4);
    double*    colsum = (double*)alloc(16*8);
    double*    zsg    = (double*)alloc(16*8);
    double*    zbg    = (double*)alloc(16*8);
    float*     out    = (float*)d_out;

    long long* gsum4 = gsum + 1024;
    long long* gsq4  = gsq  + 1024;

    prep_w<<<258, 256, 0, stream>>>(w0, w1, w2, w3, w4, wb0p, wbNp, w4b,
                                    gsum, gsq, gmin, gmax, colsum);

    prep_x_gemm<<<512, 512, 0, stream>>>(x, wb0p, bitsx, gsum, gsq);

    relay13<<<512, 512, 0, stream>>>(bitsx, wb0p, gsum, gsq, g0, b0,
                                     wbNp + 0*1024, bits0, gsum + 256, gsq + 256);

    relay4<<<512, 512, 0, stream>>>(bits0, wbNp + 0*1024, gsum + 256, gsq + 256, g1, b1,
                                    wbNp + 1*1024, bits1, gsum + 512, gsq + 512);

    relay4<<<512, 512, 0, stream>>>(bits1, wbNp + 1*1024, gsum + 512, gsq + 512, g2, b2,
                                    wbNp + 2*1024, bits2, gsum + 768, gsq + 768);

    final4<<<512, 512, 0, stream>>>(bits2, wbNp + 2*1024, gsum + 768, gsq + 768, g3, b3,
                                    w4b, v4, gsum4, gsq4, gmin, gmax);

    colsum_kernel<<<640, 256, 0, stream>>>(v4, gsum4, gsq4, gmin, gmax, g4, b4,
                                           zsg, zbg, colsum);

    out_kernel<<<2560, 256, 0, stream>>>(v4, zsg, zbg, colsum, out);
}

// Round 9
// 295.130 us; speedup vs baseline: 1.0617x; 1.0617x over previous
//
#include <hip/hip_runtime.h>
#include <cstdint>
#include <climits>
#include <cstddef>

typedef unsigned long long u64;

#define B_ROWS 65536
#define BN_EPS 1e-5

// ---------------------------------------------------------------------------
// Layouts (float4-interleaved everywhere, verified absmax=0 rounds 3-8):
//   activations layer0 in: 13 words/row; word k=4*cg+e (cg<3): bit l <-> col
//     cg*256+4l+e; word 12 = cols 768..783 as 4 nibbles.
//   activations layers1..4 in: 4 words/row; word e: bit l <-> col 4l+e.
//   weights e-plane: wbXp[((c&7)*KW + k)*32 + (c>>3)] = word k of out-col c
//     (GEMM thread ct reads cols 8ct..8ct+7 => c&7=e, c>>3=ct, stride-8B).
//   w4b[c*4+e] interleaved words (broadcast reads).
//   v (pre-BN ints) int16 [row][256], written as uint4 (coalesced);
//   v4 int16 [row][10].
// Pipeline: prep_w -> fused0 (x-pack+L0 stats GEMM+v) -> mid x3
// (thresholds -> rebinarize v -> GEMM -> stats -> v in place) -> layer4 ->
// colsum -> out. Exact integer math end-to-end.
// ---------------------------------------------------------------------------

// ---------------------------------------------------------------------------
// prep_w: pack all weights + zero stat accumulators. Grid 258.
// ---------------------------------------------------------------------------
__global__ __launch_bounds__(256) void prep_w(
    const float* __restrict__ w0, const float* __restrict__ w1,
    const float* __restrict__ w2, const float* __restrict__ w3,
    const float* __restrict__ w4,
    u64* __restrict__ wb0p, u64* __restrict__ wbTp, u64* __restrict__ w4b,
    long long* gsum, long long* gsq, int* gmin, int* gmax, double* colsum)
{
    const int lane = threadIdx.x & 63;
    const int wv   = threadIdx.x >> 6;
    const int b    = blockIdx.x;

    if (b < 64) {
        // ---- w0 -> interleaved e-plane (13 words) ----
        const int c  = b * 4 + wv;
        const int pb = (c & 7) * 13;
        const int g  = c >> 3;
        const float4* row = (const float4*)(w0 + (size_t)c * 784);
#pragma unroll
        for (int cg = 0; cg < 3; ++cg) {
            const float4 f = row[cg*64 + lane];
            const u64 e0 = __ballot(f.x >= 0.0f);
            const u64 e1 = __ballot(f.y >= 0.0f);
            const u64 e2 = __ballot(f.z >= 0.0f);
            const u64 e3 = __ballot(f.w >= 0.0f);
            if (lane == 0) {
                wb0p[(pb + cg*4+0)*32 + g] = e0;
                wb0p[(pb + cg*4+1)*32 + g] = e1;
                wb0p[(pb + cg*4+2)*32 + g] = e2;
                wb0p[(pb + cg*4+3)*32 + g] = e3;
            }
        }
        float4 f = make_float4(-1.f, -1.f, -1.f, -1.f);
        if (lane < 4) f = row[192 + lane];
        const u64 e0 = __ballot(f.x >= 0.0f) & 0xF;
        const u64 e1 = __ballot(f.y >= 0.0f) & 0xF;
        const u64 e2 = __ballot(f.z >= 0.0f) & 0xF;
        const u64 e3 = __ballot(f.w >= 0.0f) & 0xF;
        if (lane == 0) wb0p[(pb + 12)*32 + g] = e0 | (e1 << 4) | (e2 << 8) | (e3 << 12);
    } else if (b < 256) {
        // ---- w1..w3 -> interleaved e-plane (4 words) ----
        const int idx = (b - 64) * 4 + wv;           // 0..767
        const int L = idx >> 8, c = idx & 255;
        const float* ws = (L == 0) ? w1 : (L == 1) ? w2 : w3;
        const float4 f = *(const float4*)(ws + (size_t)c * 256 + 4*lane);
        const u64 e0 = __ballot(f.x >= 0.0f);
        const u64 e1 = __ballot(f.y >= 0.0f);
        const u64 e2 = __ballot(f.z >= 0.0f);
        const u64 e3 = __ballot(f.w >= 0.0f);
        if (lane == 0) {
            const int pb = (c & 7) * 4;
            const int g  = c >> 3;
            wbTp[L*1024 + (pb+0)*32 + g] = e0;
            wbTp[L*1024 + (pb+1)*32 + g] = e1;
            wbTp[L*1024 + (pb+2)*32 + g] = e2;
            wbTp[L*1024 + (pb+3)*32 + g] = e3;
        }
    } else if (b == 256) {
        for (int c = wv; c < 10; c += 4) {
            const float4 f = *(const float4*)(w4 + (size_t)c * 256 + 4*lane);
            const u64 e0 = __ballot(f.x >= 0.0f);
            const u64 e1 = __ballot(f.y >= 0.0f);
            const u64 e2 = __ballot(f.z >= 0.0f);
            const u64 e3 = __ballot(f.w >= 0.0f);
            if (lane == 0) {
                w4b[c*4+0] = e0; w4b[c*4+1] = e1;
                w4b[c*4+2] = e2; w4b[c*4+3] = e3;
            }
        }
    } else {
        for (int i = threadIdx.x; i < 1040; i += 256) { gsum[i] = 0; gsq[i] = 0; }
        if (threadIdx.x < 16) {
            gmin[threadIdx.x] = INT_MAX;
            gmax[threadIdx.x] = INT_MIN;
            colsum[threadIdx.x] = 0.0;
        }
    }
}

// ---------------------------------------------------------------------------
// bn_threshold: exact integer binarization threshold from exact stats.
// ---------------------------------------------------------------------------
__device__ __forceinline__ void bn_threshold(long long sv, long long qv,
    float gaf, float bef, int& sg, int& t)
{
    const double mean = (double)sv / (double)B_ROWS;
    double var = (double)qv / (double)B_ROWS - mean * mean;
    if (var < 0.0) var = 0.0;
    const double rs    = 1.0 / sqrt(var + BN_EPS);
    const double scale = (double)gaf * rs;
    const double bt    = (double)bef;
    if (scale > 0.0) {
        const double tt = fmin(fmax(mean - bt / scale, -1e6), 1e6);
        sg = 1; t = (int)ceil(tt);
    } else if (scale < 0.0) {
        const double tt = fmin(fmax(mean - bt / scale, -1e6), 1e6);
        sg = -1; t = (int)(-floor(tt));
    } else { sg = 0; t = (bt >= 0.0) ? INT_MIN : 1; }
}

// ---------------------------------------------------------------------------
// gemm32: 32 rows x 256 cols popcount GEMM from LDS (sA col-major [k*32+r]),
// coalesced v stores + exact per-col stats.
// 256 thr: ct=tid&31 -> cols 8ct..+7; rt=tid>>5 -> rows rt+8j (j<4).
// A reads: 2-addr broadcast/wave (free). W reads: stride-8B e-plane (free).
// Counts packed 2/u32 (max 832 < 2^16). Per-row store = uint4 (8x int16),
// lanes 0..31 contiguous 512B. Stats: shfl_xor(32) fold -> LDS atomics ->
// 256 global atomics per block.
// ---------------------------------------------------------------------------
template<int KW>
__device__ __forceinline__ void gemm32(const u64* __restrict__ sA,
    const u64* __restrict__ sWp, int K, int row0,
    short* __restrict__ vout, long long* gsumL, long long* gsqL,
    int* sS, int* sQ)
{
    const int tid = threadIdx.x;
    const int ct  = tid & 31;
    const int rt  = tid >> 5;          // 0..7

    unsigned p2[4][4];
#pragma unroll
    for (int j = 0; j < 4; ++j)
#pragma unroll
        for (int e2 = 0; e2 < 4; ++e2) p2[j][e2] = 0;

#pragma unroll 1
    for (int k = 0; k < KW; ++k) {
        u64 a[4];
#pragma unroll
        for (int j = 0; j < 4; ++j) a[j] = sA[k*32 + rt + 8*j];
        u64 w[8];
#pragma unroll
        for (int e = 0; e < 8; ++e) w[e] = sWp[(e*KW + k)*32 + ct];
#pragma unroll
        for (int j = 0; j < 4; ++j)
#pragma unroll
            for (int e2 = 0; e2 < 4; ++e2)
                p2[j][e2] += (unsigned)__popcll(a[j] ^ w[2*e2])
                           + ((unsigned)__popcll(a[j] ^ w[2*e2+1]) << 16);
    }

    int s8[8], q8[8];
#pragma unroll
    for (int e = 0; e < 8; ++e) { s8[e] = 0; q8[e] = 0; }

#pragma unroll
    for (int j = 0; j < 4; ++j) {
        const int r = row0 + rt + 8*j;
        unsigned pk[4];
#pragma unroll
        for (int e2 = 0; e2 < 4; ++e2) {
            const int v0 = K - 2 * (int)(p2[j][e2] & 0xFFFFu);
            const int v1 = K - 2 * (int)(p2[j][e2] >> 16);
            s8[2*e2]   += v0; q8[2*e2]   += v0*v0;
            s8[2*e2+1] += v1; q8[2*e2+1] += v1*v1;
            pk[e2] = (unsigned)(unsigned short)(short)v0
                   | ((unsigned)(unsigned short)(short)v1 << 16);
        }
        *(uint4*)(vout + (size_t)r * 256 + 8*ct) = make_uint4(pk[0], pk[1], pk[2], pk[3]);
    }

#pragma unroll
    for (int e = 0; e < 8; ++e) {
        s8[e] += __shfl_xor(s8[e], 32);
        q8[e] += __shfl_xor(q8[e], 32);
    }
    if ((tid & 63) < 32) {
#pragma unroll
        for (int e = 0; e < 8; ++e) {
            atomicAdd(&sS[8*ct + e], s8[e]);
            atomicAdd(&sQ[8*ct + e], q8[e]);
        }
    }
    __syncthreads();
    atomicAdd((u64*)&gsumL[tid], (u64)(long long)sS[tid]);
    atomicAdd((u64*)&gsqL[tid],  (u64)(long long)sQ[tid]);
}

// ---------------------------------------------------------------------------
// fused0: x-pack (32 rows, interleaved words -> LDS col-major) + layer-0
// stats GEMM + v0 write. 2048 blocks x 256 thr; LDS 32KB -> 5 blocks/CU, so
// co-resident blocks at different phases keep HBM and VALU both busy.
// ---------------------------------------------------------------------------
__global__ __launch_bounds__(256, 5) void fused0(
    const float* __restrict__ x, const u64* __restrict__ wb0p,
    short* __restrict__ v, long long* gsum, long long* gsq)
{
    __shared__ __align__(16) u64 sA[13*32];
    __shared__ __align__(16) u64 sWp[13*8*32];
    __shared__ int sS[256], sQ[256];
    const int tid  = threadIdx.x;
    const int lane = tid & 63;
    const int wv   = tid >> 6;          // 0..3
    const int row0 = blockIdx.x * 32;

    for (int i = tid; i < 13*8*32; i += 256) sWp[i] = wb0p[i];
    sS[tid] = 0; sQ[tid] = 0;

#pragma unroll 2
    for (int i = 0; i < 8; ++i) {
        const int r   = wv * 8 + i;
        const float4* xr = (const float4*)(x + (size_t)(row0 + r) * 784);
#pragma unroll
        for (int cg = 0; cg < 3; ++cg) {
            const float4 f = xr[cg*64 + lane];
            const u64 e0 = __ballot(f.x >= 0.5f);
            const u64 e1 = __ballot(f.y >= 0.5f);
            const u64 e2 = __ballot(f.z >= 0.5f);
            const u64 e3 = __ballot(f.w >= 0.5f);
            if (lane == 0) {
                sA[(cg*4+0)*32 + r] = e0;
                sA[(cg*4+1)*32 + r] = e1;
                sA[(cg*4+2)*32 + r] = e2;
                sA[(cg*4+3)*32 + r] = e3;
            }
        }
        float4 f = make_float4(-1.f, -1.f, -1.f, -1.f);
        if (lane < 4) f = xr[192 + lane];
        const u64 e0 = __ballot(f.x >= 0.5f) & 0xF;
        const u64 e1 = __ballot(f.y >= 0.5f) & 0xF;
        const u64 e2 = __ballot(f.z >= 0.5f) & 0xF;
        const u64 e3 = __ballot(f.w >= 0.5f) & 0xF;
        if (lane == 0) sA[12*32 + r] = e0 | (e1 << 4) | (e2 << 8) | (e3 << 12);
    }
    __syncthreads();
    gemm32<13>(sA, sWp, 784, row0, v, gsum, gsq, sS, sQ);
}

// ---------------------------------------------------------------------------
// layer_mid: thresholds (redundant/block, exact) -> rebinarize 32 v-rows in
// LDS (interleaved words) -> GEMM -> stats -> v in place. 2048 x 256,
// LDS 13KB -> 24 waves/CU.
// ---------------------------------------------------------------------------
__global__ __launch_bounds__(256, 6) void layer_mid(
    short* v,
    const long long* __restrict__ gsumP, const long long* __restrict__ gsqP,
    const float* __restrict__ gaP, const float* __restrict__ beP,
    const u64* __restrict__ wbTpL, long long* gsumC, long long* gsqC)
{
    __shared__ __align__(16) u64 sA[4*32];
    __shared__ __align__(16) u64 sWp[4*8*32];
    __shared__ int sSgn[256], sThr[256];
    __shared__ int sS[256], sQ[256];
    const int tid  = threadIdx.x;
    const int lane = tid & 63;
    const int wv   = tid >> 6;
    const int row0 = blockIdx.x * 32;

    for (int i = tid; i < 4*8*32; i += 256) sWp[i] = wbTpL[i];
    {
        int sg, t;
        bn_threshold(gsumP[tid], gsqP[tid], gaP[tid], beP[tid], sg, t);
        sSgn[tid] = sg; sThr[tid] = t;
        sS[tid] = 0; sQ[tid] = 0;
    }
    __syncthreads();

    const int4 sg4 = *(const int4*)&sSgn[4*lane];
    const int4 th4 = *(const int4*)&sThr[4*lane];
#pragma unroll 2
    for (int i = 0; i < 8; ++i) {
        const int r = wv * 8 + i;
        const short4 vv = *(const short4*)(v + (size_t)(row0 + r)*256 + 4*lane);
        const u64 e0 = __ballot(sg4.x * (int)vv.x >= th4.x);
        const u64 e1 = __ballot(sg4.y * (int)vv.y >= th4.y);
        const u64 e2 = __ballot(sg4.z * (int)vv.z >= th4.z);
        const u64 e3 = __ballot(sg4.w * (int)vv.w >= th4.w);
        if (lane == 0) {
            sA[0*32 + r] = e0; sA[1*32 + r] = e1;
            sA[2*32 + r] = e2; sA[3*32 + r] = e3;
        }
    }
    __syncthreads();
    gemm32<4>(sA, sWp, 256, row0, v, gsumC, gsqC, sS, sQ);
}

// ---------------------------------------------------------------------------
// layer4: 512 x 512, 16 rows/wave, no LDS round-trip (proven round 7):
// ballots -> lane c<10 popcounts class c -> v4 + exact sum/sq/min/max.
// ---------------------------------------------------------------------------
__global__ __launch_bounds__(512) void layer4_kernel(
    const short* __restrict__ v,
    const long long* __restrict__ gsumP, const long long* __restrict__ gsqP,
    const float* __restrict__ gaP, const float* __restrict__ beP,
    const u64* __restrict__ w4b, short* __restrict__ v4,
    long long* gsum4, long long* gsq4, int* gmin, int* gmax)
{
    __shared__ int sSgn[256], sThr[256];
    __shared__ int sS[10], sQ[10], sMn[10], sMx[10];
    const int tid  = threadIdx.x;
    const int lane = tid & 63;
    const int wv   = tid >> 6;          // 0..7

    if (tid < 256) {
        int sg, t;
        bn_threshold(gsumP[tid], gsqP[tid], gaP[tid], beP[tid], sg, t);
        sSgn[tid] = sg; sThr[tid] = t;
    }
    if (tid < 10) { sS[tid] = 0; sQ[tid] = 0; sMn[tid] = INT_MAX; sMx[tid] = INT_MIN; }
    __syncthreads();

    const int4 sg4 = *(const int4*)&sSgn[4*lane];
    const int4 th4 = *(const int4*)&sThr[4*lane];

    u64 wc0 = 0, wc1 = 0, wc2 = 0, wc3 = 0;
    if (lane < 10) {
        wc0 = w4b[lane*4+0]; wc1 = w4b[lane*4+1];
        wc2 = w4b[lane*4+2]; wc3 = w4b[lane*4+3];
    }

    int accS = 0, accQ = 0, mn = INT_MAX, mx = INT_MIN;
    const int waveId = blockIdx.x * 8 + wv;           // 0..4095
    const int r0 = waveId * 16;
#pragma unroll 2
    for (int i = 0; i < 16; ++i) {
        const int r = r0 + i;
        const short4 vv = *(const short4*)(v + (size_t)r*256 + 4*lane);
        const u64 e0 = __ballot(sg4.x * (int)vv.x >= th4.x);
        const u64 e1 = __ballot(sg4.y * (int)vv.y >= th4.y);
        const u64 e2 = __ballot(sg4.z * (int)vv.z >= th4.z);
        const u64 e3 = __ballot(sg4.w * (int)vv.w >= th4.w);
        if (lane < 10) {
            const int p = (int)__popcll(e0 ^ wc0) + (int)__popcll(e1 ^ wc1)
                        + (int)__popcll(e2 ^ wc2) + (int)__popcll(e3 ^ wc3);
            const int vr = 256 - 2*p;
            v4[(size_t)r*10 + lane] = (short)vr;
            accS += vr; accQ += vr*vr;
            mn = min(mn, vr); mx = max(mx, vr);
        }
    }
    if (lane < 10) {
        atomicAdd(&sS[lane], accS);
        atomicAdd(&sQ[lane], accQ);
        atomicMin(&sMn[lane], mn);
        atomicMax(&sMx[lane], mx);
    }
    __syncthreads();
    if (tid < 10) {
        atomicAdd((u64*)&gsum4[tid], (u64)(long long)sS[tid]);
        atomicAdd((u64*)&gsq4[tid],  (u64)(long long)sQ[tid]);
        atomicMin(&gmin[tid], sMn[tid]);
        atomicMax(&gmax[tid], sMx[tid]);
    }
}

// ---------------------------------------------------------------------------
// colsum_kernel: zs/zb (exact from integer min/max) + partial exp-sums.
// float expf on double-computed argument, double accumulation (err ~1e-7).
// ---------------------------------------------------------------------------
__global__ __launch_bounds__(256) void colsum_kernel(
    const short* __restrict__ v4,
    const long long* __restrict__ gsum4, const long long* __restrict__ gsq4,
    const int* __restrict__ gmin, const int* __restrict__ gmax,
    const float* __restrict__ g4, const float* __restrict__ b4,
    double* zsg, double* zbg, double* colsum)
{
    __shared__ double sred[256];
    __shared__ double sZ[2];
    const int c     = blockIdx.x % 10;
    const int chunk = blockIdx.x / 10;
    const int tid   = threadIdx.x;
    if (tid == 0) {
        const double mean = (double)gsum4[c] / (double)B_ROWS;
        double var = (double)gsq4[c] / (double)B_ROWS - mean * mean;
        if (var < 0.0) var = 0.0;
        const double rs    = 1.0 / sqrt(var + BN_EPS);
        const double scale = (double)g4[c] * rs;
        const double bias  = (double)b4[c] - mean * scale;
        const double z1 = scale * (double)gmin[c] + bias;
        const double z2 = scale * (double)gmax[c] + bias;
        const double zb = bias - fmax(z1, z2);
        sZ[0] = scale; sZ[1] = zb;
        zsg[c] = scale; zbg[c] = zb;       // redundant identical writes, benign
    }
    __syncthreads();
    const double zs = sZ[0], zb = sZ[1];
    double acc = 0.0;
    const int r0 = chunk * 1024;
#pragma unroll
    for (int j = 0; j < 4; ++j) {
        const int r = r0 + j*256 + tid;
        acc += (double)expf((float)(zs * (double)v4[(size_t)r*10 + c] + zb));
    }
    sred[tid] = acc; __syncthreads();
    for (int s = 128; s > 0; s >>= 1) {
        if (tid < s) sred[tid] += sred[tid + s];
        __syncthreads();
    }
    if (tid == 0) atomicAdd(&colsum[c], sred[0]);
}

// ---------------------------------------------------------------------------
// out_kernel: out = expf(zs*v + zb) / colsum, coalesced.
// ---------------------------------------------------------------------------
__global__ __launch_bounds__(256) void out_kernel(
    const short* __restrict__ v4, const double* __restrict__ zsg,
    const double* __restrict__ zbg, const double* __restrict__ colsum,
    float* __restrict__ out)
{
    const int idx = blockIdx.x * 256 + threadIdx.x;
    if (idx >= B_ROWS * 10) return;
    const int c = idx % 10;
    const float e = expf((float)(zsg[c] * (double)v4[idx] + zbg[c]));
    out[idx] = (float)((double)e / colsum[c]);
}

// ---------------------------------------------------------------------------
extern "C" void kernel_launch(void* const* d_in, const int* in_sizes, int n_in,
                              void* d_out, int out_size, void* d_ws, size_t ws_size,
                              hipStream_t stream)
{
    const float* x  = (const float*)d_in[0];
    const float* w0 = (const float*)d_in[1];
    const float* g0 = (const float*)d_in[2];
    const float* b0 = (const float*)d_in[3];
    const float* w1 = (const float*)d_in[4];
    const float* g1 = (const float*)d_in[5];
    const float* b1 = (const float*)d_in[6];
    const float* w2 = (const float*)d_in[7];
    const float* g2 = (const float*)d_in[8];
    const float* b2 = (const float*)d_in[9];
    const float* w3 = (const float*)d_in[10];
    const float* g3 = (const float*)d_in[11];
    const float* b3 = (const float*)d_in[12];
    const float* w4 = (const float*)d_in[13];
    const float* g4 = (const float*)d_in[14];
    const float* b4 = (const float*)d_in[15];

    char* p = (char*)d_ws;
    auto alloc = [&](size_t bytes) -> char* {
        char* r = p;
        p += (bytes + 255) & ~(size_t)255;
        return r;
    };
    u64*       wb0p   = (u64*)alloc(13*8*32*8);
    u64*       wbTp   = (u64*)alloc(3*1024*8);
    u64*       w4b    = (u64*)alloc(40*8);
    short*     v      = (short*)alloc(65536ull*256*2);
    short*     v4     = (short*)alloc(65536ull*10*2);
    long long* gsum   = (long long*)alloc(1040*8);
    long long* gsq    = (long long*)alloc(1040*8);
    int*       gmin   = (int*)alloc(16*4);
    int*       gmax   = (int*)alloc(16*4);
    double*    colsum = (double*)alloc(16*8);
    double*    zsg    = (double*)alloc(16*8);
    double*    zbg    = (double*)alloc(16*8);
    float*     out    = (float*)d_out;

    long long* gsum4 = gsum + 1024;
    long long* gsq4  = gsq  + 1024;

    prep_w<<<258, 256, 0, stream>>>(w0, w1, w2, w3, w4, wb0p, wbTp, w4b,
                                    gsum, gsq, gmin, gmax, colsum);

    fused0<<<2048, 256, 0, stream>>>(x, wb0p, v, gsum, gsq);

    layer_mid<<<2048, 256, 0, stream>>>(v, gsum, gsq, g0, b0,
                                        wbTp + 0*1024, gsum + 256, gsq + 256);
    layer_mid<<<2048, 256, 0, stream>>>(v, gsum + 256, gsq + 256, g1, b1,
                                        wbTp + 1*1024, gsum + 512, gsq + 512);
    layer_mid<<<2048, 256, 0, stream>>>(v, gsum + 512, gsq + 512, g2, b2,
                                        wbTp + 2*1024, gsum + 768, gsq + 768);

    layer4_kernel<<<512, 512, 0, stream>>>(v, gsum + 768, gsq + 768, g3, b3,
                                           w4b, v4, gsum4, gsq4, gmin, gmax);

    colsum_kernel<<<640, 256, 0, stream>>>(v4, gsum4, gsq4, gmin, gmax, g4, b4,
                                           zsg, zbg, colsum);

    out_kernel<<<2560, 256, 0, stream>>>(v4, zsg, zbg, colsum, out);
}

// Round 10
// 294.383 us; speedup vs baseline: 1.0644x; 1.0025x over previous
//
#include <hip/hip_runtime.h>
#include <cstdint>
#include <climits>
#include <cstddef>

typedef unsigned long long u64;

#define B_ROWS 65536
#define BN_EPS 1e-5

// ---------------------------------------------------------------------------
// Layouts (verified absmax=0 across rounds 3-9):
//   bitsx: 13 words/row INTERLEAVED (word k=4*cg+e: bit l <-> col cg*256+4l+e;
//     word 12 = cols 768..783 as 4 nibbles), global col-major [k*65536+row].
//   bits1 (input of L1): 4 words INTERLEAVED (word e: bit l <-> col 4l+e),
//     col-major. bits2/bits3: NATURAL (word W bit b <-> col 64W+b), col-major.
//   Weight e-planes: wbXp[((c&7)*KW + k)*32 + (c>>3)] = word k of out-col c.
//     wb0p/wbI1 interleaved; wbN2/wbN3 natural; w4b[c*4+W] natural broadcast.
//   v exists only for layer 0 (int16 [row][256], coalesced uint4 stores).
// Pipeline: prep_all -> layer0v (v+stats0) -> mid1 (v->bits1 + stats1) ->
// relay4 (bits1->bits2 + stats2) -> relay4 (bits2->bits3 + stats3) ->
// final4 (bits3 -> v4 + stats4) -> colsum -> out. Exact integer math.
// ---------------------------------------------------------------------------

// ---------------------------------------------------------------------------
// prep_all: pure pack kernel. x (0..2047), w0 (2048..2111), w1 (2112..2175),
// w2 (2176..2239), w3 (2240..2303), w4 (2304), zero stats (2305).
// ---------------------------------------------------------------------------
__global__ __launch_bounds__(256) void prep_all(
    const float* __restrict__ x, const float* __restrict__ w0,
    const float* __restrict__ w1, const float* __restrict__ w2,
    const float* __restrict__ w3, const float* __restrict__ w4,
    u64* __restrict__ bitsx, u64* __restrict__ wb0p, u64* __restrict__ wbI1,
    u64* __restrict__ wbN2, u64* __restrict__ wbN3, u64* __restrict__ w4b,
    long long* gsum, long long* gsq, int* gmin, int* gmax, double* colsum)
{
    const int lane = threadIdx.x & 63;
    const int wv   = threadIdx.x >> 6;
    const int b    = blockIdx.x;

    if (b < 2048) {
        // ---- x pack: wave per 8 rows, interleaved words, col-major out ----
        const int gw = b * 4 + wv;
        for (int i = 0; i < 8; ++i) {
            const int row = gw * 8 + i;
            const float4* xr = (const float4*)(x + (size_t)row * 784);
#pragma unroll
            for (int cg = 0; cg < 3; ++cg) {
                const float4 f = xr[cg*64 + lane];
                const u64 e0 = __ballot(f.x >= 0.5f);
                const u64 e1 = __ballot(f.y >= 0.5f);
                const u64 e2 = __ballot(f.z >= 0.5f);
                const u64 e3 = __ballot(f.w >= 0.5f);
                if (lane == 0) {
                    bitsx[(size_t)(cg*4+0)*65536 + row] = e0;
                    bitsx[(size_t)(cg*4+1)*65536 + row] = e1;
                    bitsx[(size_t)(cg*4+2)*65536 + row] = e2;
                    bitsx[(size_t)(cg*4+3)*65536 + row] = e3;
                }
            }
            float4 f = make_float4(-1.f, -1.f, -1.f, -1.f);
            if (lane < 4) f = xr[192 + lane];
            const u64 e0 = __ballot(f.x >= 0.5f) & 0xF;
            const u64 e1 = __ballot(f.y >= 0.5f) & 0xF;
            const u64 e2 = __ballot(f.z >= 0.5f) & 0xF;
            const u64 e3 = __ballot(f.w >= 0.5f) & 0xF;
            if (lane == 0)
                bitsx[(size_t)12*65536 + row] = e0 | (e1 << 4) | (e2 << 8) | (e3 << 12);
        }
    } else if (b < 2112) {
        // ---- w0 -> interleaved e-plane (13 words) ----
        const int c  = (b - 2048) * 4 + wv;
        const int pb = (c & 7) * 13;
        const int g  = c >> 3;
        const float4* row = (const float4*)(w0 + (size_t)c * 784);
#pragma unroll
        for (int cg = 0; cg < 3; ++cg) {
            const float4 f = row[cg*64 + lane];
            const u64 e0 = __ballot(f.x >= 0.0f);
            const u64 e1 = __ballot(f.y >= 0.0f);
            const u64 e2 = __ballot(f.z >= 0.0f);
            const u64 e3 = __ballot(f.w >= 0.0f);
            if (lane == 0) {
                wb0p[(pb + cg*4+0)*32 + g] = e0;
                wb0p[(pb + cg*4+1)*32 + g] = e1;
                wb0p[(pb + cg*4+2)*32 + g] = e2;
                wb0p[(pb + cg*4+3)*32 + g] = e3;
            }
        }
        float4 f = make_float4(-1.f, -1.f, -1.f, -1.f);
        if (lane < 4) f = row[192 + lane];
        const u64 e0 = __ballot(f.x >= 0.0f) & 0xF;
        const u64 e1 = __ballot(f.y >= 0.0f) & 0xF;
        const u64 e2 = __ballot(f.z >= 0.0f) & 0xF;
        const u64 e3 = __ballot(f.w >= 0.0f) & 0xF;
        if (lane == 0) wb0p[(pb + 12)*32 + g] = e0 | (e1 << 4) | (e2 << 8) | (e3 << 12);
    } else if (b < 2176) {
        // ---- w1 -> interleaved e-plane (4 words) ----
        const int c = (b - 2112) * 4 + wv;
        const float4 f = *(const float4*)(w1 + (size_t)c * 256 + 4*lane);
        const u64 e0 = __ballot(f.x >= 0.0f);
        const u64 e1 = __ballot(f.y >= 0.0f);
        const u64 e2 = __ballot(f.z >= 0.0f);
        const u64 e3 = __ballot(f.w >= 0.0f);
        if (lane == 0) {
            const int pb = (c & 7) * 4;
            const int g  = c >> 3;
            wbI1[(pb+0)*32 + g] = e0;
            wbI1[(pb+1)*32 + g] = e1;
            wbI1[(pb+2)*32 + g] = e2;
            wbI1[(pb+3)*32 + g] = e3;
        }
    } else if (b < 2304) {
        // ---- w2/w3 -> natural e-plane (4 words) ----
        const int idx = (b - 2176) * 4 + wv;     // 0..511
        const int L = idx >> 8, c = idx & 255;
        const float* ws = (L == 0) ? w2 : w3;
        u64* wbN = (L == 0) ? wbN2 : wbN3;
        const int pb = (c & 7) * 4;
        const int g  = c >> 3;
#pragma unroll
        for (int W = 0; W < 4; ++W) {
            const u64 m = __ballot(ws[(size_t)c * 256 + W*64 + lane] >= 0.0f);
            if (lane == 0) wbN[(pb + W)*32 + g] = m;
        }
    } else if (b == 2304) {
        // ---- w4 -> natural words ----
        for (int c = wv; c < 10; c += 4)
#pragma unroll
            for (int W = 0; W < 4; ++W) {
                const u64 m = __ballot(w4[(size_t)c * 256 + W*64 + lane] >= 0.0f);
                if (lane == 0) w4b[c*4 + W] = m;
            }
    } else {
        for (int i = threadIdx.x; i < 1040; i += 256) { gsum[i] = 0; gsq[i] = 0; }
        if (threadIdx.x < 16) {
            gmin[threadIdx.x] = INT_MAX;
            gmax[threadIdx.x] = INT_MIN;
            colsum[threadIdx.x] = 0.0;
        }
    }
}

// ---------------------------------------------------------------------------
// bn_threshold: exact integer binarization threshold from exact stats.
// ---------------------------------------------------------------------------
__device__ __forceinline__ void bn_threshold(long long sv, long long qv,
    float gaf, float bef, int& sg, int& t)
{
    const double mean = (double)sv / (double)B_ROWS;
    double var = (double)qv / (double)B_ROWS - mean * mean;
    if (var < 0.0) var = 0.0;
    const double rs    = 1.0 / sqrt(var + BN_EPS);
    const double scale = (double)gaf * rs;
    const double bt    = (double)bef;
    if (scale > 0.0) {
        const double tt = fmin(fmax(mean - bt / scale, -1e6), 1e6);
        sg = 1; t = (int)ceil(tt);
    } else if (scale < 0.0) {
        const double tt = fmin(fmax(mean - bt / scale, -1e6), 1e6);
        sg = -1; t = (int)(-floor(tt));
    } else { sg = 0; t = (bt >= 0.0) ? INT_MIN : 1; }
}

// ---------------------------------------------------------------------------
// gemm_coal: 128x256 popcount GEMM, coalesced uint4 v stores + exact stats.
// (R6/R7-proven.) ct=tid&31 cols 8ct..+7; rt=tid>>5 rows rt+16j.
// ---------------------------------------------------------------------------
template<int KW>
__device__ __forceinline__ void gemm_coal(const u64* __restrict__ sA,
    const u64* __restrict__ sWp, int K, int row0,
    short* __restrict__ vout, long long* gsumL, long long* gsqL,
    int* sS, int* sQ)
{
    const int tid = threadIdx.x;
    const int ct  = tid & 31;
    const int rt  = tid >> 5;

    unsigned p2[8][4];
#pragma unroll
    for (int j = 0; j < 8; ++j)
#pragma unroll
        for (int e2 = 0; e2 < 4; ++e2) p2[j][e2] = 0;

#pragma unroll 1
    for (int k = 0; k < KW; ++k) {
        u64 a[8];
#pragma unroll
        for (int j = 0; j < 8; ++j) a[j] = sA[k*128 + rt + 16*j];
        u64 w[8];
#pragma unroll
        for (int e = 0; e < 8; ++e) w[e] = sWp[(e*KW + k)*32 + ct];
#pragma unroll
        for (int j = 0; j < 8; ++j)
#pragma unroll
            for (int e2 = 0; e2 < 4; ++e2)
                p2[j][e2] += (unsigned)__popcll(a[j] ^ w[2*e2])
                           + ((unsigned)__popcll(a[j] ^ w[2*e2+1]) << 16);
    }

    int s8[8], q8[8];
#pragma unroll
    for (int e = 0; e < 8; ++e) { s8[e] = 0; q8[e] = 0; }

#pragma unroll
    for (int j = 0; j < 8; ++j) {
        const int r = row0 + rt + 16*j;
        unsigned pk[4];
#pragma unroll
        for (int e2 = 0; e2 < 4; ++e2) {
            const int v0 = K - 2 * (int)(p2[j][e2] & 0xFFFFu);
            const int v1 = K - 2 * (int)(p2[j][e2] >> 16);
            s8[2*e2]   += v0; q8[2*e2]   += v0*v0;
            s8[2*e2+1] += v1; q8[2*e2+1] += v1*v1;
            pk[e2] = (unsigned)(unsigned short)(short)v0
                   | ((unsigned)(unsigned short)(short)v1 << 16);
        }
        *(uint4*)(vout + (size_t)r * 256 + 8*ct) = make_uint4(pk[0], pk[1], pk[2], pk[3]);
    }

#pragma unroll
    for (int e = 0; e < 8; ++e) {
        s8[e] += __shfl_xor(s8[e], 32);
        q8[e] += __shfl_xor(q8[e], 32);
    }
    if ((tid & 63) < 32) {
#pragma unroll
        for (int e = 0; e < 8; ++e) {
            atomicAdd(&sS[8*ct + e], s8[e]);
            atomicAdd(&sQ[8*ct + e], q8[e]);
        }
    }
    __syncthreads();
    if (tid < 256) {
        atomicAdd((u64*)&gsumL[tid], (u64)(long long)sS[tid]);
        atomicAdd((u64*)&gsqL[tid],  (u64)(long long)sQ[tid]);
    }
}

// ---------------------------------------------------------------------------
// gemm_stats / gemm_bin: R8-proven 128x256 GEMM variants. A indexed
// sA[k*SK + row*SR] (col-major SK=128,SR=1; row-major u64 SK=1,SR=4).
// ---------------------------------------------------------------------------
template<int KW, int SK, int SR>
__device__ __forceinline__ void gemm_stats(const u64* __restrict__ sA,
    const u64* __restrict__ sWp, int K,
    long long* gsumL, long long* gsqL, int* sS, int* sQ)
{
    const int tid = threadIdx.x;
    const int ct  = tid & 31;
    const int rt  = tid >> 5;

    unsigned p2[8][4];
#pragma unroll
    for (int j = 0; j < 8; ++j)
#pragma unroll
        for (int e2 = 0; e2 < 4; ++e2) p2[j][e2] = 0;

#pragma unroll 1
    for (int k = 0; k < KW; ++k) {
        u64 a[8];
#pragma unroll
        for (int j = 0; j < 8; ++j) a[j] = sA[k*SK + (rt + 16*j)*SR];
        u64 w[8];
#pragma unroll
        for (int e = 0; e < 8; ++e) w[e] = sWp[(e*KW + k)*32 + ct];
#pragma unroll
        for (int j = 0; j < 8; ++j)
#pragma unroll
            for (int e2 = 0; e2 < 4; ++e2)
                p2[j][e2] += (unsigned)__popcll(a[j] ^ w[2*e2])
                           + ((unsigned)__popcll(a[j] ^ w[2*e2+1]) << 16);
    }

    int s8[8], q8[8];
#pragma unroll
    for (int e = 0; e < 8; ++e) { s8[e] = 0; q8[e] = 0; }
#pragma unroll
    for (int j = 0; j < 8; ++j)
#pragma unroll
        for (int e2 = 0; e2 < 4; ++e2) {
            const int v0 = K - 2 * (int)(p2[j][e2] & 0xFFFFu);
            const int v1 = K - 2 * (int)(p2[j][e2] >> 16);
            s8[2*e2]   += v0; q8[2*e2]   += v0*v0;
            s8[2*e2+1] += v1; q8[2*e2+1] += v1*v1;
        }
#pragma unroll
    for (int e = 0; e < 8; ++e) {
        s8[e] += __shfl_xor(s8[e], 32);
        q8[e] += __shfl_xor(q8[e], 32);
    }
    if ((tid & 63) < 32) {
#pragma unroll
        for (int e = 0; e < 8; ++e) {
            atomicAdd(&sS[8*ct + e], s8[e]);
            atomicAdd(&sQ[8*ct + e], q8[e]);
        }
    }
    __syncthreads();
    if (tid < 256) {
        atomicAdd((u64*)&gsumL[tid], (u64)(long long)sS[tid]);
        atomicAdd((u64*)&gsqL[tid],  (u64)(long long)sQ[tid]);
    }
}

template<int KW, int SK, int SR>
__device__ __forceinline__ void gemm_bin(const u64* __restrict__ sA,
    const u64* __restrict__ sWp, int K,
    const int* __restrict__ sSgn, const int* __restrict__ sThr,
    unsigned char* __restrict__ sBinB)
{
    const int tid = threadIdx.x;
    const int ct  = tid & 31;
    const int rt  = tid >> 5;
    const int c0  = ct << 3;

    unsigned p2[8][4];
#pragma unroll
    for (int j = 0; j < 8; ++j)
#pragma unroll
        for (int e2 = 0; e2 < 4; ++e2) p2[j][e2] = 0;

#pragma unroll 1
    for (int k = 0; k < KW; ++k) {
        u64 a[8];
#pragma unroll
        for (int j = 0; j < 8; ++j) a[j] = sA[k*SK + (rt + 16*j)*SR];
        u64 w[8];
#pragma unroll
        for (int e = 0; e < 8; ++e) w[e] = sWp[(e*KW + k)*32 + ct];
#pragma unroll
        for (int j = 0; j < 8; ++j)
#pragma unroll
            for (int e2 = 0; e2 < 4; ++e2)
                p2[j][e2] += (unsigned)__popcll(a[j] ^ w[2*e2])
                           + ((unsigned)__popcll(a[j] ^ w[2*e2+1]) << 16);
    }

    int sg[8], th[8];
    *(int4*)&sg[0] = *(const int4*)&sSgn[c0];
    *(int4*)&sg[4] = *(const int4*)&sSgn[c0 + 4];
    *(int4*)&th[0] = *(const int4*)&sThr[c0];
    *(int4*)&th[4] = *(const int4*)&sThr[c0 + 4];

#pragma unroll
    for (int j = 0; j < 8; ++j) {
        unsigned byteV = 0;
#pragma unroll
        for (int e2 = 0; e2 < 4; ++e2) {
            const int v0 = K - 2 * (int)(p2[j][e2] & 0xFFFFu);
            const int v1 = K - 2 * (int)(p2[j][e2] >> 16);
            byteV |= (unsigned)(sg[2*e2]  *v0 >= th[2*e2])   << (2*e2);
            byteV |= (unsigned)(sg[2*e2+1]*v1 >= th[2*e2+1]) << (2*e2+1);
        }
        sBinB[(rt + 16*j)*32 + ct] = (unsigned char)byteV;
    }
}

// ---------------------------------------------------------------------------
// layer0v: stage bitsx tile + w0 e-planes, GEMM -> v (33MB) + stats0.
// (R7-proven.)
// ---------------------------------------------------------------------------
__global__ __launch_bounds__(512, 4) void layer0v(
    const u64* __restrict__ bitsx, const u64* __restrict__ wb0p,
    short* __restrict__ v, long long* gsum, long long* gsq)
{
    __shared__ __align__(16) u64 sA[13*128];
    __shared__ __align__(16) u64 sWp[13*8*32];
    __shared__ int sS[256], sQ[256];
    const int tid  = threadIdx.x;
    const int row0 = blockIdx.x * 128;
    for (int i = tid; i < 13*128; i += 512)
        sA[i] = bitsx[(size_t)(i >> 7)*65536 + row0 + (i & 127)];
    for (int i = tid; i < 13*8*32; i += 512) sWp[i] = wb0p[i];
    if (tid < 256) { sS[tid] = 0; sQ[tid] = 0; }
    __syncthreads();
    gemm_coal<13>(sA, sWp, 784, row0, v, gsum, gsq, sS, sQ);
}

// ---------------------------------------------------------------------------
// mid1: thr0 -> rebinarize v (33MB read) -> bits1 (2MB, interleaved
// col-major) + L1 stats GEMM (interleaved w1 planes).
// ---------------------------------------------------------------------------
__global__ __launch_bounds__(512, 4) void mid1(
    const short* __restrict__ v,
    const long long* __restrict__ gsumP, const long long* __restrict__ gsqP,
    const float* __restrict__ gaP, const float* __restrict__ beP,
    const u64* __restrict__ wbI1, u64* __restrict__ bits1,
    long long* gsumC, long long* gsqC)
{
    __shared__ __align__(16) u64 sA[4*128];
    __shared__ __align__(16) u64 sWp[4*8*32];
    __shared__ int sSgn[256], sThr[256];
    __shared__ int sS[256], sQ[256];
    const int tid  = threadIdx.x;
    const int lane = tid & 63;
    const int wv   = tid >> 6;
    const int row0 = blockIdx.x * 128;

    for (int i = tid; i < 4*8*32; i += 512) sWp[i] = wbI1[i];
    if (tid < 256) {
        int sg, t;
        bn_threshold(gsumP[tid], gsqP[tid], gaP[tid], beP[tid], sg, t);
        sSgn[tid] = sg; sThr[tid] = t;
        sS[tid] = 0; sQ[tid] = 0;
    }
    __syncthreads();

    const int4 sg4 = *(const int4*)&sSgn[4*lane];
    const int4 th4 = *(const int4*)&sThr[4*lane];
    for (int i = 0; i < 16; ++i) {
        const int r = wv * 16 + i;
        const short4 vv = *(const short4*)(v + (size_t)(row0 + r)*256 + 4*lane);
        const u64 e0 = __ballot(sg4.x * (int)vv.x >= th4.x);
        const u64 e1 = __ballot(sg4.y * (int)vv.y >= th4.y);
        const u64 e2 = __ballot(sg4.z * (int)vv.z >= th4.z);
        const u64 e3 = __ballot(sg4.w * (int)vv.w >= th4.w);
        if (lane == 0) {
            sA[0*128 + r] = e0; sA[1*128 + r] = e1;
            sA[2*128 + r] = e2; sA[3*128 + r] = e3;
        }
    }
    __syncthreads();

    { const int W = tid >> 7, r = tid & 127;
      bits1[(size_t)W*65536 + row0 + r] = sA[W*128 + r]; }
    gemm_stats<4, 128, 1>(sA, sWp, 256, gsumC, gsqC, sS, sQ);
}

// ---------------------------------------------------------------------------
// relay4: recompute layer (bitsIn x wbpI, thr) -> bitsOut (natural) + next
// layer stats (wbpN). (R8-proven.)
// ---------------------------------------------------------------------------
__global__ __launch_bounds__(512, 4) void relay4(
    const u64* __restrict__ bitsIn, const u64* __restrict__ wbpI,
    const long long* __restrict__ gsumP, const long long* __restrict__ gsqP,
    const float* __restrict__ gaP, const float* __restrict__ beP,
    const u64* __restrict__ wbpN, u64* __restrict__ bitsOut,
    long long* gsumC, long long* gsqC)
{
    __shared__ __align__(16) u64 sBinI[128*4];
    __shared__ __align__(16) u64 sWpI[4*8*32];
    __shared__ __align__(16) u64 sWpN[4*8*32];
    __shared__ __align__(16) u64 sBinO[128*4];
    __shared__ int sSgn[256], sThr[256], sS[256], sQ[256];
    const int tid  = threadIdx.x;
    const int row0 = blockIdx.x * 128;

    { const int W = tid >> 7, r = tid & 127;
      sBinI[r*4 + W] = bitsIn[(size_t)W*65536 + row0 + r]; }
    for (int i = tid; i < 4*8*32; i += 512) { sWpI[i] = wbpI[i]; sWpN[i] = wbpN[i]; }
    if (tid < 256) {
        int sg, t;
        bn_threshold(gsumP[tid], gsqP[tid], gaP[tid], beP[tid], sg, t);
        sSgn[tid] = sg; sThr[tid] = t;
        sS[tid] = 0; sQ[tid] = 0;
    }
    __syncthreads();

    gemm_bin<4, 1, 4>(sBinI, sWpI, 256, sSgn, sThr, (unsigned char*)sBinO);
    __syncthreads();

    { const int W = tid >> 7, r = tid & 127;
      bitsOut[(size_t)W*65536 + row0 + r] = sBinO[r*4 + W]; }
    gemm_stats<4, 1, 4>(sBinO, sWpN, 256, gsumC, gsqC, sS, sQ);
}

// ---------------------------------------------------------------------------
// final4: recompute L3 -> binarize (natural) -> L4 (10 cols) -> v4 + exact
// sum/sq/min/max. (R8-proven.)
// ---------------------------------------------------------------------------
__global__ __launch_bounds__(512, 4) void final4(
    const u64* __restrict__ bitsIn, const u64* __restrict__ wbpI,
    const long long* __restrict__ gsumP, const long long* __restrict__ gsqP,
    const float* __restrict__ gaP, const float* __restrict__ beP,
    const u64* __restrict__ w4b, short* __restrict__ v4,
    long long* gsum4, long long* gsq4, int* gmin, int* gmax)
{
    __shared__ __align__(16) u64 sBinI[128*4];
    __shared__ __align__(16) u64 sWpI[4*8*32];
    __shared__ __align__(16) u64 sBinO[128*4];
    __shared__ u64 sW4[40];
    __shared__ int sSgn[256], sThr[256];
    __shared__ int sS4[10], sQ4[10], sMn[10], sMx[10];
    const int tid  = threadIdx.x;
    const int row0 = blockIdx.x * 128;

    { const int W = tid >> 7, r = tid & 127;
      sBinI[r*4 + W] = bitsIn[(size_t)W*65536 + row0 + r]; }
    for (int i = tid; i < 4*8*32; i += 512) sWpI[i] = wbpI[i];
    if (tid < 40) sW4[tid] = w4b[tid];
    if (tid < 256) {
        int sg, t;
        bn_threshold(gsumP[tid], gsqP[tid], gaP[tid], beP[tid], sg, t);
        sSgn[tid] = sg; sThr[tid] = t;
    }
    if (tid < 10) { sS4[tid] = 0; sQ4[tid] = 0; sMn[tid] = INT_MAX; sMx[tid] = INT_MIN; }
    __syncthreads();

    gemm_bin<4, 1, 4>(sBinI, sWpI, 256, sSgn, sThr, (unsigned char*)sBinO);
    __syncthreads();

    if (tid < 128) {
        const int r = tid;
        const u64 a0 = sBinO[r*4+0], a1 = sBinO[r*4+1];
        const u64 a2 = sBinO[r*4+2], a3 = sBinO[r*4+3];
#pragma unroll
        for (int c = 0; c < 10; ++c) {
            const int p = (int)__popcll(a0 ^ sW4[c*4+0]) + (int)__popcll(a1 ^ sW4[c*4+1])
                        + (int)__popcll(a2 ^ sW4[c*4+2]) + (int)__popcll(a3 ^ sW4[c*4+3]);
            const int vr = 256 - 2*p;
            v4[(size_t)(row0 + r)*10 + c] = (short)vr;
            atomicAdd(&sS4[c], vr);
            atomicAdd(&sQ4[c], vr*vr);
            atomicMin(&sMn[c], vr);
            atomicMax(&sMx[c], vr);
        }
    }
    __syncthreads();
    if (tid < 10) {
        atomicAdd((u64*)&gsum4[tid], (u64)(long long)sS4[tid]);
        atomicAdd((u64*)&gsq4[tid],  (u64)(long long)sQ4[tid]);
        atomicMin(&gmin[tid], sMn[tid]);
        atomicMax(&gmax[tid], sMx[tid]);
    }
}

// ---------------------------------------------------------------------------
// colsum_kernel: zs/zb (exact from integer min/max) + partial exp-sums.
// ---------------------------------------------------------------------------
__global__ __launch_bounds__(256) void colsum_kernel(
    const short* __restrict__ v4,
    const long long* __restrict__ gsum4, const long long* __restrict__ gsq4,
    const int* __restrict__ gmin, const int* __restrict__ gmax,
    const float* __restrict__ g4, const float* __restrict__ b4,
    double* zsg, double* zbg, double* colsum)
{
    __shared__ double sred[256];
    __shared__ double sZ[2];
    const int c     = blockIdx.x % 10;
    const int chunk = blockIdx.x / 10;
    const int tid   = threadIdx.x;
    if (tid == 0) {
        const double mean = (double)gsum4[c] / (double)B_ROWS;
        double var = (double)gsq4[c] / (double)B_ROWS - mean * mean;
        if (var < 0.0) var = 0.0;
        const double rs    = 1.0 / sqrt(var + BN_EPS);
        const double scale = (double)g4[c] * rs;
        const double bias  = (double)b4[c] - mean * scale;
        const double z1 = scale * (double)gmin[c] + bias;
        const double z2 = scale * (double)gmax[c] + bias;
        const double zb = bias - fmax(z1, z2);
        sZ[0] = scale; sZ[1] = zb;
        zsg[c] = scale; zbg[c] = zb;       // redundant identical writes, benign
    }
    __syncthreads();
    const double zs = sZ[0], zb = sZ[1];
    double acc = 0.0;
    const int r0 = chunk * 1024;
#pragma unroll
    for (int j = 0; j < 4; ++j) {
        const int r = r0 + j*256 + tid;
        acc += (double)expf((float)(zs * (double)v4[(size_t)r*10 + c] + zb));
    }
    sred[tid] = acc; __syncthreads();
    for (int s = 128; s > 0; s >>= 1) {
        if (tid < s) sred[tid] += sred[tid + s];
        __syncthreads();
    }
    if (tid == 0) atomicAdd(&colsum[c], sred[0]);
}

// ---------------------------------------------------------------------------
// out_kernel: out = expf(zs*v + zb) / colsum, coalesced.
// ---------------------------------------------------------------------------
__global__ __launch_bounds__(256) void out_kernel(
    const short* __restrict__ v4, const double* __restrict__ zsg,
    const double* __restrict__ zbg, const double* __restrict__ colsum,
    float* __restrict__ out)
{
    const int idx = blockIdx.x * 256 + threadIdx.x;
    if (idx >= B_ROWS * 10) return;
    const int c = idx % 10;
    const float e = expf((float)(zsg[c] * (double)v4[idx] + zbg[c]));
    out[idx] = (float)((double)e / colsum[c]);
}

// ---------------------------------------------------------------------------
extern "C" void kernel_launch(void* const* d_in, const int* in_sizes, int n_in,
                              void* d_out, int out_size, void* d_ws, size_t ws_size,
                              hipStream_t stream)
{
    const float* x  = (const float*)d_in[0];
    const float* w0 = (const float*)d_in[1];
    const float* g0 = (const float*)d_in[2];
    const float* b0 = (const float*)d_in[3];
    const float* w1 = (const float*)d_in[4];
    const float* g1 = (const float*)d_in[5];
    const float* b1 = (const float*)d_in[6];
    const float* w2 = (const float*)d_in[7];
    const float* g2 = (const float*)d_in[8];
    const float* b2 = (const float*)d_in[9];
    const float* w3 = (const float*)d_in[10];
    const float* g3 = (const float*)d_in[11];
    const float* b3 = (const float*)d_in[12];
    const float* w4 = (const float*)d_in[13];
    const float* g4 = (const float*)d_in[14];
    const float* b4 = (const float*)d_in[15];

    char* p = (char*)d_ws;
    auto alloc = [&](size_t bytes) -> char* {
        char* r = p;
        p += (bytes + 255) & ~(size_t)255;
        return r;
    };
    u64*       bitsx  = (u64*)alloc(13ull*65536*8);
    u64*       bits1  = (u64*)alloc(4ull*65536*8);
    u64*       bits2  = (u64*)alloc(4ull*65536*8);
    u64*       bits3  = (u64*)alloc(4ull*65536*8);
    u64*       wb0p   = (u64*)alloc(13*8*32*8);
    u64*       wbI1   = (u64*)alloc(1024*8);
    u64*       wbN2   = (u64*)alloc(1024*8);
    u64*       wbN3   = (u64*)alloc(1024*8);
    u64*       w4b    = (u64*)alloc(40*8);
    short*     v      = (short*)alloc(65536ull*256*2);
    short*     v4     = (short*)alloc(65536ull*10*2);
    long long* gsum   = (long long*)alloc(1040*8);
    long long* gsq    = (long long*)alloc(1040*8);
    int*       gmin   = (int*)alloc(16*4);
    int*       gmax   = (int*)alloc(16*4);
    double*    colsum = (double*)alloc(16*8);
    double*    zsg    = (double*)alloc(16*8);
    double*    zbg    = (double*)alloc(16*8);
    float*     out    = (float*)d_out;

    long long* gsum4 = gsum + 1024;
    long long* gsq4  = gsq  + 1024;

    prep_all<<<2306, 256, 0, stream>>>(x, w0, w1, w2, w3, w4,
                                       bitsx, wb0p, wbI1, wbN2, wbN3, w4b,
                                       gsum, gsq, gmin, gmax, colsum);

    layer0v<<<512, 512, 0, stream>>>(bitsx, wb0p, v, gsum, gsq);

    mid1<<<512, 512, 0, stream>>>(v, gsum, gsq, g0, b0, wbI1, bits1,
                                  gsum + 256, gsq + 256);

    relay4<<<512, 512, 0, stream>>>(bits1, wbI1, gsum + 256, gsq + 256, g1, b1,
                                    wbN2, bits2, gsum + 512, gsq + 512);

    relay4<<<512, 512, 0, stream>>>(bits2, wbN2, gsum + 512, gsq + 512, g2, b2,
                                    wbN3, bits3, gsum + 768, gsq + 768);

    final4<<<512, 512, 0, stream>>>(bits3, wbN3, gsum + 768, gsq + 768, g3, b3,
                                    w4b, v4, gsum4, gsq4, gmin, gmax);

    colsum_kernel<<<640, 256, 0, stream>>>(v4, gsum4, gsq4, gmin, gmax, g4, b4,
                                           zsg, zbg, colsum);

    out_kernel<<<2560, 256, 0, stream>>>(v4, zsg, zbg, colsum, out);
}

// Round 11
// 202.710 us; speedup vs baseline: 1.5457x; 1.4522x over previous
//
#include <hip/hip_runtime.h>
#include <cstdint>
#include <climits>
#include <cstddef>

typedef unsigned long long u64;

#define B_ROWS 65536
#define BN_EPS 1e-5

// ---------------------------------------------------------------------------
// R7-proven structure (207us, absmax=0), reverted verbatim; only change:
// exp -> expf in colsum/out (verified exact in R9/R10 runs).
// Layouts (float4-interleaved, verified absmax=0 rounds 3-10):
//   x/layer0 A: 13 words/row. word k=4*cg+e (cg<3): bit l <-> col cg*256+4l+e.
//               word 12: cols 768..783 as 4 nibbles.
//   layers 1..4 A: 4 words, word e: bit l <-> col 4l+e.
//   Weights in E-PLANE layout: wbXp[((c&7)*KW + k)*32 + (c>>3)].
//   w4b[c*4+e] interleaved words (broadcast reads).
//   bitsx col-major [word][row]; v int16 [row][256] (uint4 stores);
//   v4 int16 [row][10].
// ---------------------------------------------------------------------------

// ---------------------------------------------------------------------------
// prep_all: pack x (blocks 0..2047), w0 (2048..2111), w1..w4 (2112..2306),
// zero stats (2307). Mostly HBM-bound on x.
// ---------------------------------------------------------------------------
__global__ __launch_bounds__(256) void prep_all(
    const float* __restrict__ x, const float* __restrict__ w0,
    const float* __restrict__ w1, const float* __restrict__ w2,
    const float* __restrict__ w3, const float* __restrict__ w4,
    u64* __restrict__ bitsx, u64* __restrict__ wb0p, u64* __restrict__ wbTp,
    u64* __restrict__ w4b,
    long long* gsum, long long* gsq, int* gmin, int* gmax, double* colsum)
{
    const int lane = threadIdx.x & 63;
    const int wv   = threadIdx.x >> 6;
    const int b    = blockIdx.x;

    if (b < 2048) {
        // ---- x pack: wave per 8 rows ----
        const int gw = b * 4 + wv;
        for (int i = 0; i < 8; ++i) {
            const int row = gw * 8 + i;
            const float4* xr = (const float4*)(x + (size_t)row * 784);
#pragma unroll
            for (int cg = 0; cg < 3; ++cg) {
                const float4 f = xr[cg*64 + lane];
                const u64 e0 = __ballot(f.x >= 0.5f);
                const u64 e1 = __ballot(f.y >= 0.5f);
                const u64 e2 = __ballot(f.z >= 0.5f);
                const u64 e3 = __ballot(f.w >= 0.5f);
                if (lane == 0) {
                    bitsx[(size_t)(cg*4+0)*65536 + row] = e0;
                    bitsx[(size_t)(cg*4+1)*65536 + row] = e1;
                    bitsx[(size_t)(cg*4+2)*65536 + row] = e2;
                    bitsx[(size_t)(cg*4+3)*65536 + row] = e3;
                }
            }
            float4 f = make_float4(-1.f, -1.f, -1.f, -1.f);
            if (lane < 4) f = xr[192 + lane];
            const u64 e0 = __ballot(f.x >= 0.5f) & 0xF;
            const u64 e1 = __ballot(f.y >= 0.5f) & 0xF;
            const u64 e2 = __ballot(f.z >= 0.5f) & 0xF;
            const u64 e3 = __ballot(f.w >= 0.5f) & 0xF;
            if (lane == 0)
                bitsx[(size_t)12*65536 + row] = e0 | (e1 << 4) | (e2 << 8) | (e3 << 12);
        }
    } else if (b < 2112) {
        // ---- w0 pack -> e-plane layout ----
        const int c = (b - 2048) * 4 + wv;
        const int pb = (c & 7) * 13;      // plane base
        const int g  = c >> 3;            // col group
        const float4* row = (const float4*)(w0 + (size_t)c * 784);
#pragma unroll
        for (int cg = 0; cg < 3; ++cg) {
            const float4 f = row[cg*64 + lane];
            const u64 e0 = __ballot(f.x >= 0.0f);
            const u64 e1 = __ballot(f.y >= 0.0f);
            const u64 e2 = __ballot(f.z >= 0.0f);
            const u64 e3 = __ballot(f.w >= 0.0f);
            if (lane == 0) {
                wb0p[(pb + cg*4+0)*32 + g] = e0;
                wb0p[(pb + cg*4+1)*32 + g] = e1;
                wb0p[(pb + cg*4+2)*32 + g] = e2;
                wb0p[(pb + cg*4+3)*32 + g] = e3;
            }
        }
        float4 f = make_float4(-1.f, -1.f, -1.f, -1.f);
        if (lane < 4) f = row[192 + lane];
        const u64 e0 = __ballot(f.x >= 0.0f) & 0xF;
        const u64 e1 = __ballot(f.y >= 0.0f) & 0xF;
        const u64 e2 = __ballot(f.z >= 0.0f) & 0xF;
        const u64 e3 = __ballot(f.w >= 0.0f) & 0xF;
        if (lane == 0) wb0p[(pb + 12)*32 + g] = e0 | (e1 << 4) | (e2 << 8) | (e3 << 12);
    } else if (b < 2307) {
        // ---- w1..w3 -> e-plane; w4 -> w4b[c*4+e] ----
        const int idx = (b - 2112) * 4 + wv;         // 0..779
        if (idx < 768) {
            const int L = idx >> 8, c = idx & 255;
            const float* ws = (L == 0) ? w1 : (L == 1) ? w2 : w3;
            const float4 f = *(const float4*)(ws + (size_t)c * 256 + 4*lane);
            const u64 e0 = __ballot(f.x >= 0.0f);
            const u64 e1 = __ballot(f.y >= 0.0f);
            const u64 e2 = __ballot(f.z >= 0.0f);
            const u64 e3 = __ballot(f.w >= 0.0f);
            if (lane == 0) {
                const int pb = (c & 7) * 4;
                const int g  = c >> 3;
                wbTp[L*1024 + (pb+0)*32 + g] = e0;
                wbTp[L*1024 + (pb+1)*32 + g] = e1;
                wbTp[L*1024 + (pb+2)*32 + g] = e2;
                wbTp[L*1024 + (pb+3)*32 + g] = e3;
            }
        } else if (idx < 778) {
            const int c = idx - 768;
            const float4 f = *(const float4*)(w4 + (size_t)c * 256 + 4*lane);
            const u64 e0 = __ballot(f.x >= 0.0f);
            const u64 e1 = __ballot(f.y >= 0.0f);
            const u64 e2 = __ballot(f.z >= 0.0f);
            const u64 e3 = __ballot(f.w >= 0.0f);
            if (lane == 0) {
                w4b[c*4+0] = e0; w4b[c*4+1] = e1; w4b[c*4+2] = e2; w4b[c*4+3] = e3;
            }
        }
    } else {
        for (int i = threadIdx.x; i < 1040; i += 256) { gsum[i] = 0; gsq[i] = 0; }
        if (threadIdx.x < 16) {
            gmin[threadIdx.x] = INT_MAX;
            gmax[threadIdx.x] = INT_MIN;
            colsum[threadIdx.x] = 0.0;
        }
    }
}

// ---------------------------------------------------------------------------
// bn_threshold: exact integer binarization threshold from exact stats.
// ---------------------------------------------------------------------------
__device__ __forceinline__ void bn_threshold(long long sv, long long qv,
    float gaf, float bef, int& sg, int& t)
{
    const double mean = (double)sv / (double)B_ROWS;
    double var = (double)qv / (double)B_ROWS - mean * mean;
    if (var < 0.0) var = 0.0;
    const double rs    = 1.0 / sqrt(var + BN_EPS);
    const double scale = (double)gaf * rs;
    const double bt    = (double)bef;
    if (scale > 0.0) {
        const double tt = fmin(fmax(mean - bt / scale, -1e6), 1e6);
        sg = 1; t = (int)ceil(tt);
    } else if (scale < 0.0) {
        const double tt = fmin(fmax(mean - bt / scale, -1e6), 1e6);
        sg = -1; t = (int)(-floor(tt));
    } else { sg = 0; t = (bt >= 0.0) ? INT_MIN : 1; }
}

// ---------------------------------------------------------------------------
// gemm_coal: 128 rows x 256 cols popcount GEMM, COALESCED v stores.
// ct=tid&31 -> cols 8ct..8ct+7; rt=tid>>5 -> rows rt+16j (j<8).
// A: 8x ds_read_b64, 2-address broadcast (free). W: 8x ds_read_b64 from
// e-planes, stride-8B lane pattern (2-way, free). Counts packed 2/u32.
// Store: one uint4 (8x int16) per row, lanes 0..31 contiguous 512B.
// Stats: shfl_xor(32) fold -> LDS atomics -> 256 global atomics per block.
// ---------------------------------------------------------------------------
template<int KW>
__device__ __forceinline__ void gemm_coal(const u64* __restrict__ sA,
    const u64* __restrict__ sWp, int K, int row0,
    short* __restrict__ vout, long long* gsumL, long long* gsqL,
    int* sS, int* sQ)
{
    const int tid = threadIdx.x;
    const int ct  = tid & 31;
    const int rt  = tid >> 5;          // 0..15

    unsigned p2[8][4];                 // [row j][colpair e2]
#pragma unroll
    for (int j = 0; j < 8; ++j)
#pragma unroll
        for (int e2 = 0; e2 < 4; ++e2) p2[j][e2] = 0;

#pragma unroll 1
    for (int k = 0; k < KW; ++k) {
        u64 a[8];
#pragma unroll
        for (int j = 0; j < 8; ++j) a[j] = sA[k*128 + rt + 16*j];
        u64 w[8];
#pragma unroll
        for (int e = 0; e < 8; ++e) w[e] = sWp[(e*KW + k)*32 + ct];
#pragma unroll
        for (int j = 0; j < 8; ++j)
#pragma unroll
            for (int e2 = 0; e2 < 4; ++e2)
                p2[j][e2] += (unsigned)__popcll(a[j] ^ w[2*e2])
                           + ((unsigned)__popcll(a[j] ^ w[2*e2+1]) << 16);
    }

    int s8[8], q8[8];
#pragma unroll
    for (int e = 0; e < 8; ++e) { s8[e] = 0; q8[e] = 0; }

#pragma unroll
    for (int j = 0; j < 8; ++j) {
        const int r = row0 + rt + 16*j;
        unsigned pk[4];
#pragma unroll
        for (int e2 = 0; e2 < 4; ++e2) {
            const int v0 = K - 2 * (int)(p2[j][e2] & 0xFFFFu);
            const int v1 = K - 2 * (int)(p2[j][e2] >> 16);
            s8[2*e2]   += v0; q8[2*e2]   += v0*v0;
            s8[2*e2+1] += v1; q8[2*e2+1] += v1*v1;
            pk[e2] = (unsigned)(unsigned short)(short)v0
                   | ((unsigned)(unsigned short)(short)v1 << 16);
        }
        *(uint4*)(vout + (size_t)r * 256 + 8*ct) = make_uint4(pk[0], pk[1], pk[2], pk[3]);
    }

#pragma unroll
    for (int e = 0; e < 8; ++e) {
        s8[e] += __shfl_xor(s8[e], 32);
        q8[e] += __shfl_xor(q8[e], 32);
    }
    if ((tid & 63) < 32) {
#pragma unroll
        for (int e = 0; e < 8; ++e) {
            atomicAdd(&sS[8*ct + e], s8[e]);
            atomicAdd(&sQ[8*ct + e], q8[e]);
        }
    }
    __syncthreads();
    if (tid < 256) {
        atomicAdd((u64*)&gsumL[tid], (u64)(long long)sS[tid]);
        atomicAdd((u64*)&gsqL[tid],  (u64)(long long)sQ[tid]);
    }
}

// ---------------------------------------------------------------------------
// layer0_kernel: stage bitsx tile + w0 e-planes, GEMM, stats, coalesced v.
// ---------------------------------------------------------------------------
__global__ __launch_bounds__(512, 4) void layer0_kernel(
    const u64* __restrict__ bitsx, const u64* __restrict__ wb0p,
    short* __restrict__ v, long long* gsum, long long* gsq)
{
    __shared__ __align__(16) u64 sA[13*128];
    __shared__ __align__(16) u64 sWp[13*8*32];
    __shared__ int sS[256], sQ[256];
    const int tid  = threadIdx.x;
    const int row0 = blockIdx.x * 128;
    for (int i = tid; i < 13*128; i += 512)
        sA[i] = bitsx[(size_t)(i >> 7)*65536 + row0 + (i & 127)];
    for (int i = tid; i < 13*8*32; i += 512) sWp[i] = wb0p[i];
    if (tid < 256) { sS[tid] = 0; sQ[tid] = 0; }
    __syncthreads();
    gemm_coal<13>(sA, sWp, 784, row0, v, gsum, gsq, sS, sQ);
}

// ---------------------------------------------------------------------------
// layer_mid_kernel: thresholds (redundant/block, exact) -> rebinarize prev v
// in-LDS -> GEMM -> stats -> v out (in place, block-owned rows).
// ---------------------------------------------------------------------------
__global__ __launch_bounds__(512, 4) void layer_mid_kernel(
    short* v,
    const long long* __restrict__ gsumP, const long long* __restrict__ gsqP,
    const float* __restrict__ gaP, const float* __restrict__ beP,
    const u64* __restrict__ wbTpL, long long* gsumC, long long* gsqC)
{
    __shared__ __align__(16) u64 sA[4*128];
    __shared__ __align__(16) u64 sWp[4*8*32];
    __shared__ int sSgn[256], sThr[256];
    __shared__ int sS[256], sQ[256];
    const int tid  = threadIdx.x;
    const int lane = tid & 63;
    const int wv   = tid >> 6;
    const int row0 = blockIdx.x * 128;

    for (int i = tid; i < 4*8*32; i += 512) sWp[i] = wbTpL[i];
    if (tid < 256) {
        int sg, t;
        bn_threshold(gsumP[tid], gsqP[tid], gaP[tid], beP[tid], sg, t);
        sSgn[tid] = sg; sThr[tid] = t;
        sS[tid] = 0; sQ[tid] = 0;
    }
    __syncthreads();

    const int4 sg4 = *(const int4*)&sSgn[4*lane];
    const int4 th4 = *(const int4*)&sThr[4*lane];
    for (int i = 0; i < 16; ++i) {
        const int r = wv * 16 + i;
        const short4 vv = *(const short4*)(v + (size_t)(row0 + r)*256 + 4*lane);
        const u64 e0 = __ballot(sg4.x * (int)vv.x >= th4.x);
        const u64 e1 = __ballot(sg4.y * (int)vv.y >= th4.y);
        const u64 e2 = __ballot(sg4.z * (int)vv.z >= th4.z);
        const u64 e3 = __ballot(sg4.w * (int)vv.w >= th4.w);
        if (lane == 0) {
            sA[0*128 + r] = e0; sA[1*128 + r] = e1;
            sA[2*128 + r] = e2; sA[3*128 + r] = e3;
        }
    }
    __syncthreads();
    gemm_coal<4>(sA, sWp, 256, row0, v, gsumC, gsqC, sS, sQ);
}

// ---------------------------------------------------------------------------
// layer4_kernel v2 (R7-proven): 512 x 512 = 4096 waves, 16 rows/wave, no LDS
// round-trip: ballots -> lane c<10 popcounts class c -> v4 + exact stats.
// ---------------------------------------------------------------------------
__global__ __launch_bounds__(512) void layer4_kernel(
    const short* __restrict__ v,
    const long long* __restrict__ gsumP, const long long* __restrict__ gsqP,
    const float* __restrict__ gaP, const float* __restrict__ beP,
    const u64* __restrict__ w4b, short* __restrict__ v4,
    long long* gsum4, long long* gsq4, int* gmin, int* gmax)
{
    __shared__ int sSgn[256], sThr[256];
    __shared__ int sS[10], sQ[10], sMn[10], sMx[10];
    const int tid  = threadIdx.x;
    const int lane = tid & 63;
    const int wv   = tid >> 6;          // 0..7

    if (tid < 256) {
        int sg, t;
        bn_threshold(gsumP[tid], gsqP[tid], gaP[tid], beP[tid], sg, t);
        sSgn[tid] = sg; sThr[tid] = t;
    }
    if (tid < 10) { sS[tid] = 0; sQ[tid] = 0; sMn[tid] = INT_MAX; sMx[tid] = INT_MIN; }
    __syncthreads();

    const int4 sg4 = *(const int4*)&sSgn[4*lane];
    const int4 th4 = *(const int4*)&sThr[4*lane];

    u64 wc0 = 0, wc1 = 0, wc2 = 0, wc3 = 0;
    if (lane < 10) {
        wc0 = w4b[lane*4+0]; wc1 = w4b[lane*4+1];
        wc2 = w4b[lane*4+2]; wc3 = w4b[lane*4+3];
    }

    int accS = 0, accQ = 0, mn = INT_MAX, mx = INT_MIN;
    const int waveId = blockIdx.x * 8 + wv;           // 0..4095
    const int r0 = waveId * 16;
#pragma unroll 2
    for (int i = 0; i < 16; ++i) {
        const int r = r0 + i;
        const short4 vv = *(const short4*)(v + (size_t)r*256 + 4*lane);
        const u64 e0 = __ballot(sg4.x * (int)vv.x >= th4.x);
        const u64 e1 = __ballot(sg4.y * (int)vv.y >= th4.y);
        const u64 e2 = __ballot(sg4.z * (int)vv.z >= th4.z);
        const u64 e3 = __ballot(sg4.w * (int)vv.w >= th4.w);
        if (lane < 10) {
            const int p = (int)__popcll(e0 ^ wc0) + (int)__popcll(e1 ^ wc1)
                        + (int)__popcll(e2 ^ wc2) + (int)__popcll(e3 ^ wc3);
            const int vr = 256 - 2*p;
            v4[(size_t)r*10 + lane] = (short)vr;
            accS += vr; accQ += vr*vr;
            mn = min(mn, vr); mx = max(mx, vr);
        }
    }
    if (lane < 10) {
        atomicAdd(&sS[lane], accS);
        atomicAdd(&sQ[lane], accQ);
        atomicMin(&sMn[lane], mn);
        atomicMax(&sMx[lane], mx);
    }
    __syncthreads();
    if (tid < 10) {
        atomicAdd((u64*)&gsum4[tid], (u64)(long long)sS[tid]);
        atomicAdd((u64*)&gsq4[tid],  (u64)(long long)sQ[tid]);
        atomicMin(&gmin[tid], sMn[tid]);
        atomicMax(&gmax[tid], sMx[tid]);
    }
}

// ---------------------------------------------------------------------------
// colsum_kernel: zs/zb (exact from integer min/max) + partial exp-sums.
// expf on double-computed argument, double accumulation (verified exact).
// ---------------------------------------------------------------------------
__global__ __launch_bounds__(256) void colsum_kernel(
    const short* __restrict__ v4,
    const long long* __restrict__ gsum4, const long long* __restrict__ gsq4,
    const int* __restrict__ gmin, const int* __restrict__ gmax,
    const float* __restrict__ g4, const float* __restrict__ b4,
    double* zsg, double* zbg, double* colsum)
{
    __shared__ double sred[256];
    __shared__ double sZ[2];
    const int c     = blockIdx.x % 10;
    const int chunk = blockIdx.x / 10;
    const int tid   = threadIdx.x;
    if (tid == 0) {
        const double mean = (double)gsum4[c] / (double)B_ROWS;
        double var = (double)gsq4[c] / (double)B_ROWS - mean * mean;
        if (var < 0.0) var = 0.0;
        const double rs    = 1.0 / sqrt(var + BN_EPS);
        const double scale = (double)g4[c] * rs;
        const double bias  = (double)b4[c] - mean * scale;
        const double z1 = scale * (double)gmin[c] + bias;
        const double z2 = scale * (double)gmax[c] + bias;
        const double zb = bias - fmax(z1, z2);
        sZ[0] = scale; sZ[1] = zb;
        zsg[c] = scale; zbg[c] = zb;       // redundant identical writes, benign
    }
    __syncthreads();
    const double zs = sZ[0], zb = sZ[1];
    double acc = 0.0;
    const int r0 = chunk * 1024;
#pragma unroll
    for (int j = 0; j < 4; ++j) {
        const int r = r0 + j*256 + tid;
        acc += (double)expf((float)(zs * (double)v4[(size_t)r*10 + c] + zb));
    }
    sred[tid] = acc; __syncthreads();
    for (int s = 128; s > 0; s >>= 1) {
        if (tid < s) sred[tid] += sred[tid + s];
        __syncthreads();
    }
    if (tid == 0) atomicAdd(&colsum[c], sred[0]);
}

// ---------------------------------------------------------------------------
// out_kernel: out = expf(zs*v + zb) / colsum, coalesced.
// ---------------------------------------------------------------------------
__global__ __launch_bounds__(256) void out_kernel(
    const short* __restrict__ v4, const double* __restrict__ zsg,
    const double* __restrict__ zbg, const double* __restrict__ colsum,
    float* __restrict__ out)
{
    const int idx = blockIdx.x * 256 + threadIdx.x;
    if (idx >= B_ROWS * 10) return;
    const int c = idx % 10;
    const float e = expf((float)(zsg[c] * (double)v4[idx] + zbg[c]));
    out[idx] = (float)((double)e / colsum[c]);
}

// ---------------------------------------------------------------------------
extern "C" void kernel_launch(void* const* d_in, const int* in_sizes, int n_in,
                              void* d_out, int out_size, void* d_ws, size_t ws_size,
                              hipStream_t stream)
{
    const float* x  = (const float*)d_in[0];
    const float* w0 = (const float*)d_in[1];
    const float* g0 = (const float*)d_in[2];
    const float* b0 = (const float*)d_in[3];
    const float* w1 = (const float*)d_in[4];
    const float* g1 = (const float*)d_in[5];
    const float* b1 = (const float*)d_in[6];
    const float* w2 = (const float*)d_in[7];
    const float* g2 = (const float*)d_in[8];
    const float* b2 = (const float*)d_in[9];
    const float* w3 = (const float*)d_in[10];
    const float* g3 = (const float*)d_in[11];
    const float* b3 = (const float*)d_in[12];
    const float* w4 = (const float*)d_in[13];
    const float* g4 = (const float*)d_in[14];
    const float* b4 = (const float*)d_in[15];

    char* p = (char*)d_ws;
    auto alloc = [&](size_t bytes) -> char* {
        char* r = p;
        p += (bytes + 255) & ~(size_t)255;
        return r;
    };
    u64*       bitsx  = (u64*)alloc(13ull*65536*8);
    u64*       wb0p   = (u64*)alloc(13*8*32*8);
    u64*       wbTp   = (u64*)alloc(3*1024*8);
    u64*       w4b    = (u64*)alloc(40*8);
    short*     v      = (short*)alloc(65536ull*256*2);
    short*     v4     = (short*)alloc(65536ull*10*2);
    long long* gsum   = (long long*)alloc(1040*8);
    long long* gsq    = (long long*)alloc(1040*8);
    int*       gmin   = (int*)alloc(16*4);
    int*       gmax   = (int*)alloc(16*4);
    double*    colsum = (double*)alloc(16*8);
    double*    zsg    = (double*)alloc(16*8);
    double*    zbg    = (double*)alloc(16*8);
    float*     out    = (float*)d_out;

    long long* gsum4 = gsum + 1024;
    long long* gsq4  = gsq  + 1024;

    prep_all<<<2308, 256, 0, stream>>>(x, w0, w1, w2, w3, w4,
                                       bitsx, wb0p, wbTp, w4b,
                                       gsum, gsq, gmin, gmax, colsum);

    layer0_kernel<<<512, 512, 0, stream>>>(bitsx, wb0p, v, gsum, gsq);

    layer_mid_kernel<<<512, 512, 0, stream>>>(v, gsum, gsq, g0, b0,
                                              wbTp + 0*1024, gsum + 256, gsq + 256);
    layer_mid_kernel<<<512, 512, 0, stream>>>(v, gsum + 256, gsq + 256, g1, b1,
                                              wbTp + 1*1024, gsum + 512, gsq + 512);
    layer_mid_kernel<<<512, 512, 0, stream>>>(v, gsum + 512, gsq + 512, g2, b2,
                                              wbTp + 2*1024, gsum + 768, gsq + 768);

    layer4_kernel<<<512, 512, 0, stream>>>(v, gsum + 768, gsq + 768, g3, b3,
                                           w4b, v4, gsum4, gsq4, gmin, gmax);

    colsum_kernel<<<640, 256, 0, stream>>>(v4, gsum4, gsq4, gmin, gmax, g4, b4,
                                           zsg, zbg, colsum);

    out_kernel<<<2560, 256, 0, stream>>>(v4, zsg, zbg, colsum, out);
}